// Round 11
// baseline (371.197 us; speedup 1.0000x reference)
//
#include <hip/hip_runtime.h>
#include <hip/hip_bf16.h>
#include <stdint.h>

#define B_ 4
#define T_ 2048
#define C_ 1024
#define H_ 16
#define D_ 64

typedef __attribute__((ext_vector_type(8))) short bf16x8;
typedef __attribute__((ext_vector_type(4))) short short4v;
typedef __attribute__((ext_vector_type(4))) float f32x4;

static __device__ __forceinline__ short f2bf(float f) {
    union { float f; unsigned u; } v; v.f = f;
    unsigned r = v.u + 0x7fffu + ((v.u >> 16) & 1u);
    return (short)(r >> 16);
}

#define GLD_LDS16(g, l) __builtin_amdgcn_global_load_lds( \
    (const __attribute__((address_space(1))) void*)(g),   \
    (__attribute__((address_space(3))) void*)(l), 16, 0, 0)

// ---------------------------------------------------------------------------
// Packing kernels
// ---------------------------------------------------------------------------
__global__ void pack_x(const float* __restrict__ x, short* __restrict__ xb) {
    int t = blockIdx.x * blockDim.x + threadIdx.x;
    const float* src = x + (size_t)t * 8;
    float4 v0 = *(const float4*)src;
    float4 v1 = *(const float4*)(src + 4);
    bf16x8 o;
    o[0] = f2bf(v0.x); o[1] = f2bf(v0.y); o[2] = f2bf(v0.z); o[3] = f2bf(v0.w);
    o[4] = f2bf(v1.x); o[5] = f2bf(v1.y); o[6] = f2bf(v1.z); o[7] = f2bf(v1.w);
    *(bf16x8*)(xb + (size_t)t * 8) = o;
}

// wq/wk/wv [H][C][D] fp32 -> wqkv_t [N=3072][K=1024] bf16 (B^T), n=qkv*1024+h*64+d
__global__ void pack_wqkv(const float* __restrict__ wq, const float* __restrict__ wk,
                          const float* __restrict__ wv, short* __restrict__ out) {
    int tid = blockIdx.x * blockDim.x + threadIdx.x;
    int n  = tid >> 7;
    int kc = tid & 127;
    int qkv = n >> 10;
    int h = (n >> 6) & 15;
    int d = n & 63;
    const float* w = (qkv == 0) ? wq : (qkv == 1) ? wk : wv;
    const float* src = w + (size_t)h * (C_ * D_) + d;
    short* dst = out + (size_t)n * C_ + kc * 8;
#pragma unroll
    for (int j = 0; j < 8; ++j)
        dst[j] = f2bf(src[(size_t)(kc * 8 + j) * D_]);
}

__global__ void pack_wproj(const float* __restrict__ wp, short* __restrict__ out) {
    int tid = blockIdx.x * blockDim.x + threadIdx.x;
    int n  = tid >> 7;
    int kc = tid & 127;
    short* dst = out + (size_t)n * C_ + kc * 8;
#pragma unroll
    for (int j = 0; j < 8; ++j)
        dst[j] = f2bf(wp[(size_t)(kc * 8 + j) * C_ + n]);
}

// ---------------------------------------------------------------------------
// GEMM (m97 structure). MODE 1: fp32 out + bias.
// MODE 2 (r7-verified): QKV split epilogue with anti-camping swizzles:
//   Q (col<1024):      qk[row*2048 + col]                         (plain)
//   K (1024..2047):    qk[row*2048 + 1024 + (c ^ ((row&7)<<7))]   c=col-1024
//   V (>=2048):        vt[(bq*1024+cm)*2048 + (t ^ ((cm&7)<<8))]  transposed
// ---------------------------------------------------------------------------
template<int MODE>
__global__ __launch_bounds__(256)
void gemm_lds(const short* __restrict__ A, const short* __restrict__ Bt,
              void* __restrict__ Cptr, short* __restrict__ vtptr,
              const float* __restrict__ bias, int M, int N, int K) {
    __shared__ short As[128 * 32];
    __shared__ short Bs[128 * 32];
    const int tid = threadIdx.x;
    const int lane = tid & 63, wid = tid >> 6;
    const int wr = wid >> 1, wc = wid & 1;
    const int l15 = lane & 15, l4 = lane >> 4;
    const int m0 = blockIdx.y * 128, n0 = blockIdx.x * 128;

    f32x4 acc[4][4] = {};

    for (int k0 = 0; k0 < K; k0 += 32) {
#pragma unroll
        for (int p = 0; p < 2; ++p) {
            int e = p * 256 + tid;
            int r = e >> 2, c = e & 3;
            GLD_LDS16(A  + (size_t)(m0 + r) * K + k0 + c * 8, As + e * 8);
            GLD_LDS16(Bt + (size_t)(n0 + r) * K + k0 + c * 8, Bs + e * 8);
        }
        __syncthreads();
        bf16x8 af[4], bfr[4];
#pragma unroll
        for (int m = 0; m < 4; ++m)
            af[m] = *(const bf16x8*)(As + (wr * 64 + m * 16 + l15) * 32 + l4 * 8);
#pragma unroll
        for (int n = 0; n < 4; ++n)
            bfr[n] = *(const bf16x8*)(Bs + (wc * 64 + n * 16 + l15) * 32 + l4 * 8);
#pragma unroll
        for (int m = 0; m < 4; ++m)
#pragma unroll
            for (int n = 0; n < 4; ++n)
                acc[m][n] = __builtin_amdgcn_mfma_f32_16x16x32_bf16(af[m], bfr[n], acc[m][n], 0, 0, 0);
        __syncthreads();
    }

#pragma unroll
    for (int m = 0; m < 4; ++m) {
        int row_base = m0 + wr * 64 + m * 16 + l4 * 4;
#pragma unroll
        for (int n = 0; n < 4; ++n) {
            int col = n0 + wc * 64 + n * 16 + l15;
            if (MODE == 1) {
#pragma unroll
                for (int r = 0; r < 4; ++r)
                    ((float*)Cptr)[(size_t)(row_base + r) * N + col] =
                        acc[m][n][r] + bias[col];
            } else {  // MODE 2
                if (n0 < 1024) {            // Q: plain
#pragma unroll
                    for (int r = 0; r < 4; ++r)
                        ((short*)Cptr)[(size_t)(row_base + r) * 2048 + col] = f2bf(acc[m][n][r]);
                } else if (n0 < 2048) {     // K: col-swizzled per row
                    int c = col - 1024;
#pragma unroll
                    for (int r = 0; r < 4; ++r) {
                        int row = row_base + r;
                        ((short*)Cptr)[(size_t)row * 2048 + 1024 + (c ^ ((row & 7) << 7))] =
                            f2bf(acc[m][n][r]);
                    }
                } else {                    // V: transposed + t-swizzled
                    int cm = col - 2048;
                    int bq = row_base >> 11, t = row_base & 2047;
                    int tz = t ^ ((cm & 7) << 8);
                    short4v s;
                    s[0] = f2bf(acc[m][n][0]); s[1] = f2bf(acc[m][n][1]);
                    s[2] = f2bf(acc[m][n][2]); s[3] = f2bf(acc[m][n][3]);
                    *(short4v*)(vtptr + ((size_t)bq * 1024 + cm) * 2048 + tz) = s;
                }
            }
        }
    }
}

// ---------------------------------------------------------------------------
// Flash attention v11 = v6 structure (4-wave blocks, NO barriers, K/V direct
// from global) + v7's anti-camping XOR swizzles (tested clean: no
// launch_bounds cap, no spill). Ps wave-private, lgkmcnt-only ordering.
// ---------------------------------------------------------------------------
__device__ __forceinline__ void softmax_phase(
    f32x4 S[4], f32x4 O[4], float* mrow, float* srow,
    int qrow0, int s0, bool diag, int l15, int l4, short* ps) {
    float pmax[4];
#pragma unroll
    for (int r = 0; r < 4; ++r) pmax[r] = -1e30f;
#pragma unroll
    for (int n = 0; n < 4; ++n) {
#pragma unroll
        for (int r = 0; r < 4; ++r) {
            float v = S[n][r] * 0.03125f;
            if (diag) {
                int scol = s0 + n * 16 + l15;
                if (scol > qrow0 + r) v = -1e30f;
            }
            S[n][r] = v;
            pmax[r] = fmaxf(pmax[r], v);
        }
    }
#pragma unroll
    for (int r = 0; r < 4; ++r) {
        float v = pmax[r];
        v = fmaxf(v, __shfl_xor(v, 1));
        v = fmaxf(v, __shfl_xor(v, 2));
        v = fmaxf(v, __shfl_xor(v, 4));
        v = fmaxf(v, __shfl_xor(v, 8));
        pmax[r] = v;
    }
    float psum[4];
#pragma unroll
    for (int r = 0; r < 4; ++r) {
        float mnew = fmaxf(mrow[r], pmax[r]);
        float fr = __expf(mrow[r] - mnew);
        mrow[r] = mnew;
        srow[r] *= fr;
#pragma unroll
        for (int n = 0; n < 4; ++n) O[n][r] *= fr;
        psum[r] = 0.0f;
    }
#pragma unroll
    for (int n = 0; n < 4; ++n) {
#pragma unroll
        for (int r = 0; r < 4; ++r) {
            float p = __expf(S[n][r] - mrow[r]);
            psum[r] += p;
            ps[(l4 * 4 + r) * 76 + n * 16 + l15] = f2bf(p);
        }
    }
#pragma unroll
    for (int r = 0; r < 4; ++r) {
        float v = psum[r];
        v += __shfl_xor(v, 1);
        v += __shfl_xor(v, 2);
        v += __shfl_xor(v, 4);
        v += __shfl_xor(v, 8);
        srow[r] += v;
    }
}

__global__ __launch_bounds__(256)
void attn_v11(const short* __restrict__ qk, const short* __restrict__ vt,
              short* __restrict__ out) {
    const int pi = blockIdx.x;        // 0..15 (strip pair)
    const int bh = blockIdx.y;        // 0..63
    const int b = bh >> 4;
    const int h = bh & 15;
    const int qA0 = pi * 64;
    const int qB0 = (31 - pi) * 64;
    const int ntA = pi + 1;
    const int ntB = 32 - pi;
    const int tid = threadIdx.x;
    const int wave = tid >> 6;
    const int lane = tid & 63;
    const int l15 = lane & 15, l4 = lane >> 4;

    __shared__ short Ps[4][2][16][76];  // wave-private P buffers (padded)

    const size_t rs = 2 * C_;  // 2048
    const short* vtb = vt + (size_t)bh * 64 * T_;   // [d][t-swizzled]

    // Q fragments (plain layout)
    const short* qrA = qk + ((size_t)b * T_ + qA0 + wave * 16 + l15) * rs + h * 64;
    const short* qrB = qk + ((size_t)b * T_ + qB0 + wave * 16 + l15) * rs + h * 64;
    bf16x8 aqA0 = *(const bf16x8*)(qrA + l4 * 8);
    bf16x8 aqA1 = *(const bf16x8*)(qrA + 32 + l4 * 8);
    bf16x8 aqB0 = *(const bf16x8*)(qrB + l4 * 8);
    bf16x8 aqB1 = *(const bf16x8*)(qrB + 32 + l4 * 8);

    f32x4 OA[4] = {}, OB[4] = {};
    float mA[4], sA[4], mB[4], sB[4];
#pragma unroll
    for (int r = 0; r < 4; ++r) { mA[r] = mB[r] = -1e30f; sA[r] = sB[r] = 0.0f; }

    short* psB = &Ps[wave][0][0][0];
    short* psA = &Ps[wave][1][0][0];

    const int swzV = (l15 & 7) << 8;  // vt t-swizzle for d-row n*16+l15

    for (int t = 0; t < ntB; ++t) {
        const int s0 = t * 64;
        const bool actA = (t < ntA);

        // ---- K fragments (col-swizzled rows; anti-camping) ----
        bf16x8 bk0[4], bk1[4];
#pragma unroll
        for (int n = 0; n < 4; ++n) {
            const int s = s0 + n * 16 + l15;
            const int swz = (s & 7) << 7;
            const short* kr = qk + ((size_t)b * T_ + s) * rs + 1024;
            bk0[n] = *(const bf16x8*)(kr + ((h * 64 + l4 * 8) ^ swz));
            bk1[n] = *(const bf16x8*)(kr + ((h * 64 + l4 * 8 + 32) ^ swz));
        }
        // ---- V fragments from vt (t-swizzled; anti-camping) ----
        bf16x8 bv0[4], bv1[4];
#pragma unroll
        for (int n = 0; n < 4; ++n) {
            const short* vr = vtb + (size_t)(n * 16 + l15) * T_;
            bv0[n] = *(const bf16x8*)(vr + ((s0 + l4 * 8) ^ swzV));
            bv1[n] = *(const bf16x8*)(vr + ((s0 + 32 + l4 * 8) ^ swzV));
        }

        // ---- strip B: QK^T + softmax ----
        f32x4 S[4];
#pragma unroll
        for (int n = 0; n < 4; ++n) {
            f32x4 z = {};
            z = __builtin_amdgcn_mfma_f32_16x16x32_bf16(aqB0, bk0[n], z, 0, 0, 0);
            S[n] = __builtin_amdgcn_mfma_f32_16x16x32_bf16(aqB1, bk1[n], z, 0, 0, 0);
        }
        softmax_phase(S, OB, mB, sB, qB0 + wave * 16 + l4 * 4, s0, s0 == qB0,
                      l15, l4, psB);

        // ---- strip A ----
        if (actA) {
            f32x4 SA[4];
#pragma unroll
            for (int n = 0; n < 4; ++n) {
                f32x4 z = {};
                z = __builtin_amdgcn_mfma_f32_16x16x32_bf16(aqA0, bk0[n], z, 0, 0, 0);
                SA[n] = __builtin_amdgcn_mfma_f32_16x16x32_bf16(aqA1, bk1[n], z, 0, 0, 0);
            }
            softmax_phase(SA, OA, mA, sA, qA0 + wave * 16 + l4 * 4, s0, s0 == qA0,
                          l15, l4, psA);
        }

        // wave-local ordering: Ps writes land before fragment re-reads
        asm volatile("s_waitcnt lgkmcnt(0)" ::: "memory");
        __builtin_amdgcn_sched_barrier(0);

        // ---- PV strip B ----
        bf16x8 apB0 = *(const bf16x8*)(psB + l15 * 76 + l4 * 8);
        bf16x8 apB1 = *(const bf16x8*)(psB + l15 * 76 + 32 + l4 * 8);
#pragma unroll
        for (int n = 0; n < 4; ++n) {
            OB[n] = __builtin_amdgcn_mfma_f32_16x16x32_bf16(apB0, bv0[n], OB[n], 0, 0, 0);
            OB[n] = __builtin_amdgcn_mfma_f32_16x16x32_bf16(apB1, bv1[n], OB[n], 0, 0, 0);
        }
        // ---- PV strip A ----
        if (actA) {
            bf16x8 apA0 = *(const bf16x8*)(psA + l15 * 76 + l4 * 8);
            bf16x8 apA1 = *(const bf16x8*)(psA + l15 * 76 + 32 + l4 * 8);
#pragma unroll
            for (int n = 0; n < 4; ++n) {
                OA[n] = __builtin_amdgcn_mfma_f32_16x16x32_bf16(apA0, bv0[n], OA[n], 0, 0, 0);
                OA[n] = __builtin_amdgcn_mfma_f32_16x16x32_bf16(apA1, bv1[n], OA[n], 0, 0, 0);
            }
        }
    }

    // ---- normalize + store both strips ----
#pragma unroll
    for (int r = 0; r < 4; ++r) {
        int rowB = qB0 + wave * 16 + l4 * 4 + r;
        int rowA = qA0 + wave * 16 + l4 * 4 + r;
        float invB = 1.0f / sB[r];
        float invA = 1.0f / sA[r];
        size_t obB = ((size_t)b * T_ + rowB) * C_ + h * 64;
        size_t obA = ((size_t)b * T_ + rowA) * C_ + h * 64;
#pragma unroll
        for (int n = 0; n < 4; ++n) {
            out[obB + n * 16 + l15] = f2bf(OB[n][r] * invB);
            out[obA + n * 16 + l15] = f2bf(OA[n][r] * invA);
        }
    }
}

// ---------------------------------------------------------------------------
extern "C" void kernel_launch(void* const* d_in, const int* in_sizes, int n_in,
                              void* d_out, int out_size, void* d_ws, size_t ws_size,
                              hipStream_t stream) {
    const float* x     = (const float*)d_in[0];
    const float* wq    = (const float*)d_in[1];
    const float* wk    = (const float*)d_in[2];
    const float* wv    = (const float*)d_in[3];
    const float* wproj = (const float*)d_in[4];
    const float* bproj = (const float*)d_in[5];
    float* out = (float*)d_out;

    // workspace (shorts): wqkv_t | wproj_t | qk_b | vt | attn_b (xb alias)
    short* wqkv_t  = (short*)d_ws;                   // 3072*1024
    short* wproj_t = wqkv_t + 3072 * 1024;           // 1024*1024
    short* qk_b    = wproj_t + 1024 * 1024;          // 8192*2048  (Q|K)
    short* vt_b    = qk_b + (size_t)8192 * 2048;     // 64*64*2048 (V^T)
    short* attn_b  = vt_b + (size_t)64 * 64 * 2048;  // 8192*1024 (xb alias)
    short* xb      = attn_b;
    // total = 75,497,472 bytes (same as all prior rounds)

    pack_x<<<4096, 256, 0, stream>>>(x, xb);
    pack_wqkv<<<1536, 256, 0, stream>>>(wq, wk, wv, wqkv_t);
    pack_wproj<<<512, 256, 0, stream>>>(wproj, wproj_t);

    // QKV projection with split epilogue: Q plain | K swizzled | V^T swizzled
    gemm_lds<2><<<dim3(24, 64), 256, 0, stream>>>(
        xb, wqkv_t, qk_b, vt_b, nullptr, 8192, 3072, 1024);

    // flash attention: 4-wave blocks, no barriers, swizzled K/V fragments
    attn_v11<<<dim3(16, 64), 256, 0, stream>>>(qk_b, vt_b, attn_b);

    // output projection: [8192,1024] x [1024,1024] + bias -> fp32
    gemm_lds<1><<<dim3(8, 64), 256, 0, stream>>>(
        attn_b, wproj_t, out, nullptr, bproj, 8192, 1024, 1024);
}

// Round 12
// 301.557 us; speedup vs baseline: 1.2309x; 1.2309x over previous
//
#include <hip/hip_runtime.h>
#include <hip/hip_bf16.h>
#include <stdint.h>

#define B_ 4
#define T_ 2048
#define C_ 1024
#define H_ 16
#define D_ 64

typedef __attribute__((ext_vector_type(8))) short bf16x8;
typedef __attribute__((ext_vector_type(4))) short short4v;
typedef __attribute__((ext_vector_type(4))) float f32x4;

static __device__ __forceinline__ short f2bf(float f) {
    union { float f; unsigned u; } v; v.f = f;
    unsigned r = v.u + 0x7fffu + ((v.u >> 16) & 1u);
    return (short)(r >> 16);
}

#define GLD_LDS16(g, l) __builtin_amdgcn_global_load_lds( \
    (const __attribute__((address_space(1))) void*)(g),   \
    (__attribute__((address_space(3))) void*)(l), 16, 0, 0)

// ---------------------------------------------------------------------------
// pack_x (round-5 exact)
// ---------------------------------------------------------------------------
__global__ void pack_x(const float* __restrict__ x, short* __restrict__ xb) {
    int t = blockIdx.x * blockDim.x + threadIdx.x;
    const float* src = x + (size_t)t * 8;
    float4 v0 = *(const float4*)src;
    float4 v1 = *(const float4*)(src + 4);
    bf16x8 o;
    o[0] = f2bf(v0.x); o[1] = f2bf(v0.y); o[2] = f2bf(v0.z); o[3] = f2bf(v0.w);
    o[4] = f2bf(v1.x); o[5] = f2bf(v1.y); o[6] = f2bf(v1.z); o[7] = f2bf(v1.w);
    *(bf16x8*)(xb + (size_t)t * 8) = o;
}

// ---------------------------------------------------------------------------
// pack_wqkv2: coalesced LDS-transpose. Per block: one 64(c) x 64(d) tile of
// one head's weight. Reads coalesced float4 rows; writes bf16x8 rows of
// wqkv_t [n=qkv*1024+h*64+d][c] (same output as previous pack_wqkv).
// grid (16 c-tiles, 48 qkv*h), 256 threads.
// ---------------------------------------------------------------------------
__global__ void pack_wqkv2(const float* __restrict__ wq, const float* __restrict__ wk,
                           const float* __restrict__ wv, short* __restrict__ out) {
    __shared__ short tile[64][72];   // [c][d], +8 pad
    const int qh = blockIdx.y;       // 0..47
    const int qkv = qh >> 4, h = qh & 15;
    const int c0 = blockIdx.x * 64;
    const float* w = ((qkv == 0) ? wq : (qkv == 1) ? wk : wv) + (size_t)h * (C_ * D_);
    const int t = threadIdx.x;
    const int r = t >> 2;            // c offset 0..63
    const int dc = (t & 3) * 16;     // d chunk {0,16,32,48}

    const float* src = w + (size_t)(c0 + r) * D_ + dc;
#pragma unroll
    for (int j = 0; j < 4; ++j) {
        float4 v = *(const float4*)(src + j * 4);
        short4v s;
        s[0] = f2bf(v.x); s[1] = f2bf(v.y); s[2] = f2bf(v.z); s[3] = f2bf(v.w);
        *(short4v*)&tile[r][dc + j * 4] = s;
    }
    __syncthreads();

    const int d = t >> 2;            // d (output row) 0..63
    const int cc = (t & 3) * 16;     // c chunk
    bf16x8 o0, o1;
#pragma unroll
    for (int j = 0; j < 8; ++j) {
        o0[j] = tile[cc + j][d];
        o1[j] = tile[cc + 8 + j][d];
    }
    short* dst = out + ((size_t)qkv * 1024 + h * 64 + d) * C_ + c0 + cc;
    *(bf16x8*)dst = o0;
    *(bf16x8*)(dst + 8) = o1;
}

// ---------------------------------------------------------------------------
// pack_wproj2: same coalesced transpose for w_proj [1024][1024] ->
// wproj_t[n][c] = wp[c][n]. grid (16 c-tiles, 16 n-tiles), 256 threads.
// ---------------------------------------------------------------------------
__global__ void pack_wproj2(const float* __restrict__ wp, short* __restrict__ out) {
    __shared__ short tile[64][72];   // [c][n], +8 pad
    const int c0 = blockIdx.x * 64;
    const int n0 = blockIdx.y * 64;
    const int t = threadIdx.x;
    const int r = t >> 2;            // c offset
    const int nc = (t & 3) * 16;     // n chunk

    const float* src = wp + (size_t)(c0 + r) * C_ + n0 + nc;
#pragma unroll
    for (int j = 0; j < 4; ++j) {
        float4 v = *(const float4*)(src + j * 4);
        short4v s;
        s[0] = f2bf(v.x); s[1] = f2bf(v.y); s[2] = f2bf(v.z); s[3] = f2bf(v.w);
        *(short4v*)&tile[r][nc + j * 4] = s;
    }
    __syncthreads();

    const int n = t >> 2;            // n (output row) offset
    const int cc = (t & 3) * 16;     // c chunk
    bf16x8 o0, o1;
#pragma unroll
    for (int j = 0; j < 8; ++j) {
        o0[j] = tile[cc + j][n];
        o1[j] = tile[cc + 8 + j][n];
    }
    short* dst = out + (size_t)(n0 + n) * C_ + c0 + cc;
    *(bf16x8*)dst = o0;
    *(bf16x8*)(dst + 8) = o1;
}

// ---------------------------------------------------------------------------
// GEMM (m97 structure, round-5 exact)
// ---------------------------------------------------------------------------
template<bool OUT_F32>
__global__ __launch_bounds__(256)
void gemm_lds(const short* __restrict__ A, const short* __restrict__ Bt,
              void* __restrict__ Cptr, const float* __restrict__ bias,
              int M, int N, int K) {
    __shared__ short As[128 * 32];
    __shared__ short Bs[128 * 32];
    const int tid = threadIdx.x;
    const int lane = tid & 63, wid = tid >> 6;
    const int wr = wid >> 1, wc = wid & 1;
    const int l15 = lane & 15, l4 = lane >> 4;
    const int m0 = blockIdx.y * 128, n0 = blockIdx.x * 128;

    f32x4 acc[4][4] = {};

    for (int k0 = 0; k0 < K; k0 += 32) {
#pragma unroll
        for (int p = 0; p < 2; ++p) {
            int e = p * 256 + tid;
            int r = e >> 2, c = e & 3;
            GLD_LDS16(A  + (size_t)(m0 + r) * K + k0 + c * 8, As + e * 8);
            GLD_LDS16(Bt + (size_t)(n0 + r) * K + k0 + c * 8, Bs + e * 8);
        }
        __syncthreads();
        bf16x8 af[4], bfr[4];
#pragma unroll
        for (int m = 0; m < 4; ++m)
            af[m] = *(const bf16x8*)(As + (wr * 64 + m * 16 + l15) * 32 + l4 * 8);
#pragma unroll
        for (int n = 0; n < 4; ++n)
            bfr[n] = *(const bf16x8*)(Bs + (wc * 64 + n * 16 + l15) * 32 + l4 * 8);
#pragma unroll
        for (int m = 0; m < 4; ++m)
#pragma unroll
            for (int n = 0; n < 4; ++n)
                acc[m][n] = __builtin_amdgcn_mfma_f32_16x16x32_bf16(af[m], bfr[n], acc[m][n], 0, 0, 0);
        __syncthreads();
    }

#pragma unroll
    for (int m = 0; m < 4; ++m) {
        int row_base = m0 + wr * 64 + m * 16 + l4 * 4;
#pragma unroll
        for (int n = 0; n < 4; ++n) {
            int col = n0 + wc * 64 + n * 16 + l15;
#pragma unroll
            for (int r = 0; r < 4; ++r) {
                int row = row_base + r;
                float v = acc[m][n][r];
                if (OUT_F32) {
                    ((float*)Cptr)[(size_t)row * N + col] = v + (bias ? bias[col] : 0.0f);
                } else {
                    ((short*)Cptr)[(size_t)row * N + col] = f2bf(v);
                }
            }
        }
    }
}

// ---------------------------------------------------------------------------
// Flash attention v5 (round-5 exact — measured optimum, frozen)
// ---------------------------------------------------------------------------
__device__ __forceinline__ void softmax_pv_phase1(
    f32x4 S[4], f32x4 O[4], float* mrow, float* srow,
    int qrow0, int s0, bool diag, int l15, int l4, short* ps) {
    float pmax[4];
#pragma unroll
    for (int r = 0; r < 4; ++r) pmax[r] = -1e30f;
#pragma unroll
    for (int n = 0; n < 4; ++n) {
#pragma unroll
        for (int r = 0; r < 4; ++r) {
            float v = S[n][r] * 0.03125f;
            if (diag) {
                int scol = s0 + n * 16 + l15;
                if (scol > qrow0 + r) v = -1e30f;
            }
            S[n][r] = v;
            pmax[r] = fmaxf(pmax[r], v);
        }
    }
#pragma unroll
    for (int r = 0; r < 4; ++r) {
        float v = pmax[r];
        v = fmaxf(v, __shfl_xor(v, 1));
        v = fmaxf(v, __shfl_xor(v, 2));
        v = fmaxf(v, __shfl_xor(v, 4));
        v = fmaxf(v, __shfl_xor(v, 8));
        pmax[r] = v;
    }
    float psum[4];
#pragma unroll
    for (int r = 0; r < 4; ++r) {
        float mnew = fmaxf(mrow[r], pmax[r]);
        float fr = __expf(mrow[r] - mnew);
        mrow[r] = mnew;
        srow[r] *= fr;
#pragma unroll
        for (int n = 0; n < 4; ++n) O[n][r] *= fr;
        psum[r] = 0.0f;
    }
#pragma unroll
    for (int n = 0; n < 4; ++n) {
#pragma unroll
        for (int r = 0; r < 4; ++r) {
            float p = __expf(S[n][r] - mrow[r]);
            psum[r] += p;
            ps[(l4 * 4 + r) * 72 + n * 16 + l15] = f2bf(p);
        }
    }
#pragma unroll
    for (int r = 0; r < 4; ++r) {
        float v = psum[r];
        v += __shfl_xor(v, 1);
        v += __shfl_xor(v, 2);
        v += __shfl_xor(v, 4);
        v += __shfl_xor(v, 8);
        srow[r] += v;
    }
}

__global__ __launch_bounds__(256)
void attn_v5(const short* __restrict__ qkv, short* __restrict__ out) {
    const int pi = blockIdx.x;        // 0..15  (strip pair)
    const int bh = blockIdx.y;        // 0..63
    const int b = bh >> 4;
    const int h = bh & 15;
    const int qA0 = pi * 64;          // strip A (early rows)
    const int qB0 = (31 - pi) * 64;   // strip B (late rows)
    const int ntA = pi + 1;
    const int ntB = 32 - pi;
    const int tid = threadIdx.x;
    const int wave = tid >> 6;
    const int lane = tid & 63;
    const int l15 = lane & 15, l4 = lane >> 4;

    __shared__ short Vt[64][72];        // Vt[d][s] = V[s][d]
    __shared__ short Ps[4][2][16][72];  // per-wave, per-strip P buffer

    const size_t rs = 3 * C_;
    const short* qbA = qkv + ((size_t)b * T_ + qA0) * rs + h * 64;
    const short* qbB = qkv + ((size_t)b * T_ + qB0) * rs + h * 64;
    const short* kb  = qkv + (size_t)b * T_ * rs + C_ + h * 64;
    const short* vb  = qkv + (size_t)b * T_ * rs + 2 * C_ + h * 64;

    // Q fragments (A-frag: lane holds Q[l15][l4*8+j]) for both strips
    bf16x8 aqA0 = *(const bf16x8*)(qbA + (size_t)(wave * 16 + l15) * rs + l4 * 8);
    bf16x8 aqA1 = *(const bf16x8*)(qbA + (size_t)(wave * 16 + l15) * rs + 32 + l4 * 8);
    bf16x8 aqB0 = *(const bf16x8*)(qbB + (size_t)(wave * 16 + l15) * rs + l4 * 8);
    bf16x8 aqB1 = *(const bf16x8*)(qbB + (size_t)(wave * 16 + l15) * rs + 32 + l4 * 8);

    f32x4 OA[4] = {}, OB[4] = {};
    float mA[4], sA[4], mB[4], sB[4];
#pragma unroll
    for (int r = 0; r < 4; ++r) { mA[r] = mB[r] = -1e30f; sA[r] = sB[r] = 0.0f; }

    short* psB = &Ps[wave][0][0][0];
    short* psA = &Ps[wave][1][0][0];

    for (int t = 0; t < ntB; ++t) {
        const int s0 = t * 64;
        const bool actA = (t < ntA);
        __syncthreads();  // all waves done reading Vt from previous tile

        // ---- stage V (coalesced gather, b128 row writes) ----
#pragma unroll
        for (int p = 0; p < 2; ++p) {
            int e = p * 256 + tid;
            int d = e & 63, sc = e >> 6;
            bf16x8 v;
#pragma unroll
            for (int j = 0; j < 8; ++j)
                v[j] = vb[(size_t)(s0 + sc * 8 + j) * rs + d];
            *(bf16x8*)&Vt[d][sc * 8] = v;
        }

        // ---- K fragments, shared by both strips ----
        bf16x8 bk0[4], bk1[4];
#pragma unroll
        for (int n = 0; n < 4; ++n) {
            const short* kr = kb + (size_t)(s0 + n * 16 + l15) * rs;
            bk0[n] = *(const bf16x8*)(kr + l4 * 8);
            bk1[n] = *(const bf16x8*)(kr + 32 + l4 * 8);
        }

        // ---- strip B: S = Q K^T, softmax, P->LDS ----
        f32x4 S[4];
#pragma unroll
        for (int n = 0; n < 4; ++n) {
            f32x4 z = {};
            z = __builtin_amdgcn_mfma_f32_16x16x32_bf16(aqB0, bk0[n], z, 0, 0, 0);
            S[n] = __builtin_amdgcn_mfma_f32_16x16x32_bf16(aqB1, bk1[n], z, 0, 0, 0);
        }
        softmax_pv_phase1(S, OB, mB, sB, qB0 + wave * 16 + l4 * 4, s0,
                          s0 == qB0, l15, l4, psB);

        // ---- strip A (while active) ----
        if (actA) {
            f32x4 SA[4];
#pragma unroll
            for (int n = 0; n < 4; ++n) {
                f32x4 z = {};
                z = __builtin_amdgcn_mfma_f32_16x16x32_bf16(aqA0, bk0[n], z, 0, 0, 0);
                SA[n] = __builtin_amdgcn_mfma_f32_16x16x32_bf16(aqA1, bk1[n], z, 0, 0, 0);
            }
            softmax_pv_phase1(SA, OA, mA, sA, qA0 + wave * 16 + l4 * 4, s0,
                              s0 == qA0, l15, l4, psA);
        }

        __syncthreads();  // Vt staged; Ps writes drained by barrier

        // ---- PV for strip B ----
        bf16x8 apB0 = *(const bf16x8*)(psB + l15 * 72 + l4 * 8);
        bf16x8 apB1 = *(const bf16x8*)(psB + l15 * 72 + 32 + l4 * 8);
#pragma unroll
        for (int n = 0; n < 4; ++n) {
            bf16x8 bv0 = *(const bf16x8*)&Vt[n * 16 + l15][l4 * 8];
            bf16x8 bv1 = *(const bf16x8*)&Vt[n * 16 + l15][32 + l4 * 8];
            OB[n] = __builtin_amdgcn_mfma_f32_16x16x32_bf16(apB0, bv0, OB[n], 0, 0, 0);
            OB[n] = __builtin_amdgcn_mfma_f32_16x16x32_bf16(apB1, bv1, OB[n], 0, 0, 0);
        }
        // ---- PV for strip A ----
        if (actA) {
            bf16x8 apA0 = *(const bf16x8*)(psA + l15 * 72 + l4 * 8);
            bf16x8 apA1 = *(const bf16x8*)(psA + l15 * 72 + 32 + l4 * 8);
#pragma unroll
            for (int n = 0; n < 4; ++n) {
                bf16x8 bv0 = *(const bf16x8*)&Vt[n * 16 + l15][l4 * 8];
                bf16x8 bv1 = *(const bf16x8*)&Vt[n * 16 + l15][32 + l4 * 8];
                OA[n] = __builtin_amdgcn_mfma_f32_16x16x32_bf16(apA0, bv0, OA[n], 0, 0, 0);
                OA[n] = __builtin_amdgcn_mfma_f32_16x16x32_bf16(apA1, bv1, OA[n], 0, 0, 0);
            }
        }
    }

    // ---- normalize + store both strips ----
#pragma unroll
    for (int r = 0; r < 4; ++r) {
        int rowB = qB0 + wave * 16 + l4 * 4 + r;
        int rowA = qA0 + wave * 16 + l4 * 4 + r;
        float invB = 1.0f / sB[r];
        float invA = 1.0f / sA[r];
        size_t obB = ((size_t)b * T_ + rowB) * C_ + h * 64;
        size_t obA = ((size_t)b * T_ + rowA) * C_ + h * 64;
#pragma unroll
        for (int n = 0; n < 4; ++n) {
            out[obB + n * 16 + l15] = f2bf(OB[n][r] * invB);
            out[obA + n * 16 + l15] = f2bf(OA[n][r] * invA);
        }
    }
}

// ---------------------------------------------------------------------------
extern "C" void kernel_launch(void* const* d_in, const int* in_sizes, int n_in,
                              void* d_out, int out_size, void* d_ws, size_t ws_size,
                              hipStream_t stream) {
    const float* x     = (const float*)d_in[0];
    const float* wq    = (const float*)d_in[1];
    const float* wk    = (const float*)d_in[2];
    const float* wv    = (const float*)d_in[3];
    const float* wproj = (const float*)d_in[4];
    const float* bproj = (const float*)d_in[5];
    float* out = (float*)d_out;

    // workspace layout (shorts): wqkv_t | wproj_t | qkv | attn_b (also xb)
    short* wqkv_t  = (short*)d_ws;                  // 3072*1024
    short* wproj_t = wqkv_t + 3072 * 1024;          // 1024*1024
    short* qkv_b   = wproj_t + 1024 * 1024;         // 8192*3072
    short* attn_b  = qkv_b + (size_t)8192 * 3072;   // 8192*1024 (xb aliased here)
    short* xb      = attn_b;                        // x bf16, dead after gemm1
    // total = 75,497,472 bytes

    pack_x<<<4096, 256, 0, stream>>>(x, xb);
    pack_wqkv2<<<dim3(16, 48), 256, 0, stream>>>(wq, wk, wv, wqkv_t);
    pack_wproj2<<<dim3(16, 16), 256, 0, stream>>>(wproj, wproj_t);

    // QKV projection: [8192,1024] x [1024,3072] -> bf16
    gemm_lds<false><<<dim3(24, 64), 256, 0, stream>>>(
        xb, wqkv_t, qkv_b, nullptr, 8192, 3072, 1024);

    // flash attention, causal-paired strips (round-5 frozen)
    attn_v5<<<dim3(16, 64), 256, 0, stream>>>(qkv_b, attn_b);

    // output projection: [8192,1024] x [1024,1024] + bias -> fp32
    gemm_lds<true><<<dim3(8, 64), 256, 0, stream>>>(
        attn_b, wproj_t, out, bproj, 8192, 1024, 1024);
}

// Round 13
// 296.981 us; speedup vs baseline: 1.2499x; 1.0154x over previous
//
#include <hip/hip_runtime.h>
#include <hip/hip_bf16.h>
#include <stdint.h>

#define B_ 4
#define T_ 2048
#define C_ 1024
#define H_ 16
#define D_ 64

typedef __attribute__((ext_vector_type(8))) short bf16x8;
typedef __attribute__((ext_vector_type(4))) short short4v;
typedef __attribute__((ext_vector_type(4))) float f32x4;

static __device__ __forceinline__ short f2bf(float f) {
    union { float f; unsigned u; } v; v.f = f;
    unsigned r = v.u + 0x7fffu + ((v.u >> 16) & 1u);
    return (short)(r >> 16);
}

static __device__ __forceinline__ float fast_exp2(float x) {
    float r;
    asm("v_exp_f32 %0, %1" : "=v"(r) : "v"(x));
    return r;
}

#define GLD_LDS16(g, l) __builtin_amdgcn_global_load_lds( \
    (const __attribute__((address_space(1))) void*)(g),   \
    (__attribute__((address_space(3))) void*)(l), 16, 0, 0)

// Q pre-scale: (1/32) * log2(e) — folds softmax scale AND exp->exp2 conversion
#define QSCALE 0.04508422f

// ---------------------------------------------------------------------------
// pack_x (round-5 exact)
// ---------------------------------------------------------------------------
__global__ void pack_x(const float* __restrict__ x, short* __restrict__ xb) {
    int t = blockIdx.x * blockDim.x + threadIdx.x;
    const float* src = x + (size_t)t * 8;
    float4 v0 = *(const float4*)src;
    float4 v1 = *(const float4*)(src + 4);
    bf16x8 o;
    o[0] = f2bf(v0.x); o[1] = f2bf(v0.y); o[2] = f2bf(v0.z); o[3] = f2bf(v0.w);
    o[4] = f2bf(v1.x); o[5] = f2bf(v1.y); o[6] = f2bf(v1.z); o[7] = f2bf(v1.w);
    *(bf16x8*)(xb + (size_t)t * 8) = o;
}

// ---------------------------------------------------------------------------
// pack_wqkv2 / pack_wproj2 (round-12 exact, coalesced LDS-transpose)
// ---------------------------------------------------------------------------
__global__ void pack_wqkv2(const float* __restrict__ wq, const float* __restrict__ wk,
                           const float* __restrict__ wv, short* __restrict__ out) {
    __shared__ short tile[64][72];
    const int qh = blockIdx.y;
    const int qkv = qh >> 4, h = qh & 15;
    const int c0 = blockIdx.x * 64;
    const float* w = ((qkv == 0) ? wq : (qkv == 1) ? wk : wv) + (size_t)h * (C_ * D_);
    const int t = threadIdx.x;
    const int r = t >> 2;
    const int dc = (t & 3) * 16;

    const float* src = w + (size_t)(c0 + r) * D_ + dc;
#pragma unroll
    for (int j = 0; j < 4; ++j) {
        float4 v = *(const float4*)(src + j * 4);
        short4v s;
        s[0] = f2bf(v.x); s[1] = f2bf(v.y); s[2] = f2bf(v.z); s[3] = f2bf(v.w);
        *(short4v*)&tile[r][dc + j * 4] = s;
    }
    __syncthreads();

    const int d = t >> 2;
    const int cc = (t & 3) * 16;
    bf16x8 o0, o1;
#pragma unroll
    for (int j = 0; j < 8; ++j) {
        o0[j] = tile[cc + j][d];
        o1[j] = tile[cc + 8 + j][d];
    }
    short* dst = out + ((size_t)qkv * 1024 + h * 64 + d) * C_ + c0 + cc;
    *(bf16x8*)dst = o0;
    *(bf16x8*)(dst + 8) = o1;
}

__global__ void pack_wproj2(const float* __restrict__ wp, short* __restrict__ out) {
    __shared__ short tile[64][72];
    const int c0 = blockIdx.x * 64;
    const int n0 = blockIdx.y * 64;
    const int t = threadIdx.x;
    const int r = t >> 2;
    const int nc = (t & 3) * 16;

    const float* src = wp + (size_t)(c0 + r) * C_ + n0 + nc;
#pragma unroll
    for (int j = 0; j < 4; ++j) {
        float4 v = *(const float4*)(src + j * 4);
        short4v s;
        s[0] = f2bf(v.x); s[1] = f2bf(v.y); s[2] = f2bf(v.z); s[3] = f2bf(v.w);
        *(short4v*)&tile[r][nc + j * 4] = s;
    }
    __syncthreads();

    const int n = t >> 2;
    const int cc = (t & 3) * 16;
    bf16x8 o0, o1;
#pragma unroll
    for (int j = 0; j < 8; ++j) {
        o0[j] = tile[cc + j][n];
        o1[j] = tile[cc + 8 + j][n];
    }
    short* dst = out + (size_t)(n0 + n) * C_ + c0 + cc;
    *(bf16x8*)dst = o0;
    *(bf16x8*)(dst + 8) = o1;
}

// ---------------------------------------------------------------------------
// GEMM (m97 structure). MODE 1: fp32 out + bias.
// MODE 2: bf16 out; Q columns (col<1024) pre-scaled by QSCALE (v9-verified).
// ---------------------------------------------------------------------------
template<int MODE>
__global__ __launch_bounds__(256)
void gemm_lds(const short* __restrict__ A, const short* __restrict__ Bt,
              void* __restrict__ Cptr, const float* __restrict__ bias,
              int M, int N, int K) {
    __shared__ short As[128 * 32];
    __shared__ short Bs[128 * 32];
    const int tid = threadIdx.x;
    const int lane = tid & 63, wid = tid >> 6;
    const int wr = wid >> 1, wc = wid & 1;
    const int l15 = lane & 15, l4 = lane >> 4;
    const int m0 = blockIdx.y * 128, n0 = blockIdx.x * 128;

    f32x4 acc[4][4] = {};

    for (int k0 = 0; k0 < K; k0 += 32) {
#pragma unroll
        for (int p = 0; p < 2; ++p) {
            int e = p * 256 + tid;
            int r = e >> 2, c = e & 3;
            GLD_LDS16(A  + (size_t)(m0 + r) * K + k0 + c * 8, As + e * 8);
            GLD_LDS16(Bt + (size_t)(n0 + r) * K + k0 + c * 8, Bs + e * 8);
        }
        __syncthreads();
        bf16x8 af[4], bfr[4];
#pragma unroll
        for (int m = 0; m < 4; ++m)
            af[m] = *(const bf16x8*)(As + (wr * 64 + m * 16 + l15) * 32 + l4 * 8);
#pragma unroll
        for (int n = 0; n < 4; ++n)
            bfr[n] = *(const bf16x8*)(Bs + (wc * 64 + n * 16 + l15) * 32 + l4 * 8);
#pragma unroll
        for (int m = 0; m < 4; ++m)
#pragma unroll
            for (int n = 0; n < 4; ++n)
                acc[m][n] = __builtin_amdgcn_mfma_f32_16x16x32_bf16(af[m], bfr[n], acc[m][n], 0, 0, 0);
        __syncthreads();
    }

#pragma unroll
    for (int m = 0; m < 4; ++m) {
        int row_base = m0 + wr * 64 + m * 16 + l4 * 4;
#pragma unroll
        for (int n = 0; n < 4; ++n) {
            int col = n0 + wc * 64 + n * 16 + l15;
#pragma unroll
            for (int r = 0; r < 4; ++r) {
                int row = row_base + r;
                float v = acc[m][n][r];
                if (MODE == 1) {
                    ((float*)Cptr)[(size_t)row * N + col] = v + bias[col];
                } else {
                    if (col < 1024) v *= QSCALE;   // Q pre-scale
                    ((short*)Cptr)[(size_t)row * N + col] = f2bf(v);
                }
            }
        }
    }
}

// ---------------------------------------------------------------------------
// Flash attention v13 = round-5 EXACT structure/layouts (stride-72 Ps, plain
// Vt) + exp2-domain softmax (Q pre-scaled) + defer-max (THR=8, log2 units).
// Single mechanism vs round 12: softmax arithmetic only.
// ---------------------------------------------------------------------------
__device__ __forceinline__ void softmax_pv_phase1(
    f32x4 S[4], f32x4 O[4], float* mrow, float* srow,
    int qrow0, int s0, bool diag, int l15, int l4, short* ps) {
    float pmax[4];
#pragma unroll
    for (int r = 0; r < 4; ++r) pmax[r] = -1e30f;
#pragma unroll
    for (int n = 0; n < 4; ++n) {
#pragma unroll
        for (int r = 0; r < 4; ++r) {
            float v = S[n][r];   // already scaled + in log2 domain
            if (diag) {
                int scol = s0 + n * 16 + l15;
                if (scol > qrow0 + r) v = -1e30f;
            }
            S[n][r] = v;
            pmax[r] = fmaxf(pmax[r], v);
        }
    }
#pragma unroll
    for (int r = 0; r < 4; ++r) {
        float v = pmax[r];
        v = fmaxf(v, __shfl_xor(v, 1));
        v = fmaxf(v, __shfl_xor(v, 2));
        v = fmaxf(v, __shfl_xor(v, 4));
        v = fmaxf(v, __shfl_xor(v, 8));
        pmax[r] = v;
    }
    // defer-max: skip O/s rescale while max growth <= 8 (P bounded by 2^8)
    int ok = (pmax[0] <= mrow[0] + 8.0f) & (pmax[1] <= mrow[1] + 8.0f) &
             (pmax[2] <= mrow[2] + 8.0f) & (pmax[3] <= mrow[3] + 8.0f);
    if (!__all(ok)) {
#pragma unroll
        for (int r = 0; r < 4; ++r) {
            float mnew = fmaxf(mrow[r], pmax[r]);
            float fr = fast_exp2(mrow[r] - mnew);
            mrow[r] = mnew;
            srow[r] *= fr;
#pragma unroll
            for (int n = 0; n < 4; ++n) O[n][r] *= fr;
        }
    }
    float psum[4];
#pragma unroll
    for (int r = 0; r < 4; ++r) psum[r] = 0.0f;
#pragma unroll
    for (int n = 0; n < 4; ++n) {
#pragma unroll
        for (int r = 0; r < 4; ++r) {
            float p = fast_exp2(S[n][r] - mrow[r]);
            psum[r] += p;
            ps[(l4 * 4 + r) * 72 + n * 16 + l15] = f2bf(p);
        }
    }
#pragma unroll
    for (int r = 0; r < 4; ++r) {
        float v = psum[r];
        v += __shfl_xor(v, 1);
        v += __shfl_xor(v, 2);
        v += __shfl_xor(v, 4);
        v += __shfl_xor(v, 8);
        srow[r] += v;
    }
}

__global__ __launch_bounds__(256)
void attn_v13(const short* __restrict__ qkv, short* __restrict__ out) {
    const int pi = blockIdx.x;        // 0..15  (strip pair)
    const int bh = blockIdx.y;        // 0..63
    const int b = bh >> 4;
    const int h = bh & 15;
    const int qA0 = pi * 64;
    const int qB0 = (31 - pi) * 64;
    const int ntA = pi + 1;
    const int ntB = 32 - pi;
    const int tid = threadIdx.x;
    const int wave = tid >> 6;
    const int lane = tid & 63;
    const int l15 = lane & 15, l4 = lane >> 4;

    __shared__ short Vt[64][72];        // Vt[d][s] = V[s][d]  (v5 layout)
    __shared__ short Ps[4][2][16][72];  // per-wave, per-strip P buffer (v5)

    const size_t rs = 3 * C_;
    const short* qbA = qkv + ((size_t)b * T_ + qA0) * rs + h * 64;
    const short* qbB = qkv + ((size_t)b * T_ + qB0) * rs + h * 64;
    const short* kb  = qkv + (size_t)b * T_ * rs + C_ + h * 64;
    const short* vb  = qkv + (size_t)b * T_ * rs + 2 * C_ + h * 64;

    bf16x8 aqA0 = *(const bf16x8*)(qbA + (size_t)(wave * 16 + l15) * rs + l4 * 8);
    bf16x8 aqA1 = *(const bf16x8*)(qbA + (size_t)(wave * 16 + l15) * rs + 32 + l4 * 8);
    bf16x8 aqB0 = *(const bf16x8*)(qbB + (size_t)(wave * 16 + l15) * rs + l4 * 8);
    bf16x8 aqB1 = *(const bf16x8*)(qbB + (size_t)(wave * 16 + l15) * rs + 32 + l4 * 8);

    f32x4 OA[4] = {}, OB[4] = {};
    float mA[4], sA[4], mB[4], sB[4];
#pragma unroll
    for (int r = 0; r < 4; ++r) { mA[r] = mB[r] = -1e30f; sA[r] = sB[r] = 0.0f; }

    short* psB = &Ps[wave][0][0][0];
    short* psA = &Ps[wave][1][0][0];

    for (int t = 0; t < ntB; ++t) {
        const int s0 = t * 64;
        const bool actA = (t < ntA);
        __syncthreads();  // all waves done reading Vt from previous tile

        // ---- stage V (coalesced gather, b128 row writes; v5 exact) ----
#pragma unroll
        for (int p = 0; p < 2; ++p) {
            int e = p * 256 + tid;
            int d = e & 63, sc = e >> 6;
            bf16x8 v;
#pragma unroll
            for (int j = 0; j < 8; ++j)
                v[j] = vb[(size_t)(s0 + sc * 8 + j) * rs + d];
            *(bf16x8*)&Vt[d][sc * 8] = v;
        }

        // ---- K fragments, shared by both strips ----
        bf16x8 bk0[4], bk1[4];
#pragma unroll
        for (int n = 0; n < 4; ++n) {
            const short* kr = kb + (size_t)(s0 + n * 16 + l15) * rs;
            bk0[n] = *(const bf16x8*)(kr + l4 * 8);
            bk1[n] = *(const bf16x8*)(kr + 32 + l4 * 8);
        }

        // ---- strip B: S = Q K^T, softmax, P->LDS ----
        f32x4 S[4];
#pragma unroll
        for (int n = 0; n < 4; ++n) {
            f32x4 z = {};
            z = __builtin_amdgcn_mfma_f32_16x16x32_bf16(aqB0, bk0[n], z, 0, 0, 0);
            S[n] = __builtin_amdgcn_mfma_f32_16x16x32_bf16(aqB1, bk1[n], z, 0, 0, 0);
        }
        softmax_pv_phase1(S, OB, mB, sB, qB0 + wave * 16 + l4 * 4, s0,
                          s0 == qB0, l15, l4, psB);

        // ---- strip A (while active) ----
        if (actA) {
            f32x4 SA[4];
#pragma unroll
            for (int n = 0; n < 4; ++n) {
                f32x4 z = {};
                z = __builtin_amdgcn_mfma_f32_16x16x32_bf16(aqA0, bk0[n], z, 0, 0, 0);
                SA[n] = __builtin_amdgcn_mfma_f32_16x16x32_bf16(aqA1, bk1[n], z, 0, 0, 0);
            }
            softmax_pv_phase1(SA, OA, mA, sA, qA0 + wave * 16 + l4 * 4, s0,
                              s0 == qA0, l15, l4, psA);
        }

        __syncthreads();  // Vt staged; Ps writes drained by barrier

        // ---- PV for strip B ----
        bf16x8 apB0 = *(const bf16x8*)(psB + l15 * 72 + l4 * 8);
        bf16x8 apB1 = *(const bf16x8*)(psB + l15 * 72 + 32 + l4 * 8);
#pragma unroll
        for (int n = 0; n < 4; ++n) {
            bf16x8 bv0 = *(const bf16x8*)&Vt[n * 16 + l15][l4 * 8];
            bf16x8 bv1 = *(const bf16x8*)&Vt[n * 16 + l15][32 + l4 * 8];
            OB[n] = __builtin_amdgcn_mfma_f32_16x16x32_bf16(apB0, bv0, OB[n], 0, 0, 0);
            OB[n] = __builtin_amdgcn_mfma_f32_16x16x32_bf16(apB1, bv1, OB[n], 0, 0, 0);
        }
        // ---- PV for strip A ----
        if (actA) {
            bf16x8 apA0 = *(const bf16x8*)(psA + l15 * 72 + l4 * 8);
            bf16x8 apA1 = *(const bf16x8*)(psA + l15 * 72 + 32 + l4 * 8);
#pragma unroll
            for (int n = 0; n < 4; ++n) {
                bf16x8 bv0 = *(const bf16x8*)&Vt[n * 16 + l15][l4 * 8];
                bf16x8 bv1 = *(const bf16x8*)&Vt[n * 16 + l15][32 + l4 * 8];
                OA[n] = __builtin_amdgcn_mfma_f32_16x16x32_bf16(apA0, bv0, OA[n], 0, 0, 0);
                OA[n] = __builtin_amdgcn_mfma_f32_16x16x32_bf16(apA1, bv1, OA[n], 0, 0, 0);
            }
        }
    }

    // ---- normalize + store both strips ----
#pragma unroll
    for (int r = 0; r < 4; ++r) {
        int rowB = qB0 + wave * 16 + l4 * 4 + r;
        int rowA = qA0 + wave * 16 + l4 * 4 + r;
        float invB = 1.0f / sB[r];
        float invA = 1.0f / sA[r];
        size_t obB = ((size_t)b * T_ + rowB) * C_ + h * 64;
        size_t obA = ((size_t)b * T_ + rowA) * C_ + h * 64;
#pragma unroll
        for (int n = 0; n < 4; ++n) {
            out[obB + n * 16 + l15] = f2bf(OB[n][r] * invB);
            out[obA + n * 16 + l15] = f2bf(OA[n][r] * invA);
        }
    }
}

// ---------------------------------------------------------------------------
extern "C" void kernel_launch(void* const* d_in, const int* in_sizes, int n_in,
                              void* d_out, int out_size, void* d_ws, size_t ws_size,
                              hipStream_t stream) {
    const float* x     = (const float*)d_in[0];
    const float* wq    = (const float*)d_in[1];
    const float* wk    = (const float*)d_in[2];
    const float* wv    = (const float*)d_in[3];
    const float* wproj = (const float*)d_in[4];
    const float* bproj = (const float*)d_in[5];
    float* out = (float*)d_out;

    // workspace layout (shorts): wqkv_t | wproj_t | qkv | attn_b (also xb)
    short* wqkv_t  = (short*)d_ws;                  // 3072*1024
    short* wproj_t = wqkv_t + 3072 * 1024;          // 1024*1024
    short* qkv_b   = wproj_t + 1024 * 1024;         // 8192*3072
    short* attn_b  = qkv_b + (size_t)8192 * 3072;   // 8192*1024 (xb aliased here)
    short* xb      = attn_b;                        // x bf16, dead after gemm1
    // total = 75,497,472 bytes

    pack_x<<<4096, 256, 0, stream>>>(x, xb);
    pack_wqkv2<<<dim3(16, 48), 256, 0, stream>>>(wq, wk, wv, wqkv_t);
    pack_wproj2<<<dim3(16, 16), 256, 0, stream>>>(wproj, wproj_t);

    // QKV projection: [8192,1024] x [1024,3072] -> bf16 (Q cols pre-scaled)
    gemm_lds<2><<<dim3(24, 64), 256, 0, stream>>>(
        xb, wqkv_t, qkv_b, nullptr, 8192, 3072, 1024);

    // flash attention, causal-paired strips, exp2 softmax + defer-max
    attn_v13<<<dim3(16, 64), 256, 0, stream>>>(qkv_b, attn_b);

    // output projection: [8192,1024] x [1024,1024] + bias -> fp32
    gemm_lds<1><<<dim3(8, 64), 256, 0, stream>>>(
        attn_b, wproj_t, out, bproj, 8192, 1024, 1024);
}

// Round 14
// 288.683 us; speedup vs baseline: 1.2858x; 1.0287x over previous
//
#include <hip/hip_runtime.h>
#include <hip/hip_bf16.h>
#include <stdint.h>

#define B_ 4
#define T_ 2048
#define C_ 1024
#define H_ 16
#define D_ 64

typedef __attribute__((ext_vector_type(8))) short bf16x8;
typedef __attribute__((ext_vector_type(4))) short short4v;
typedef __attribute__((ext_vector_type(4))) float f32x4;

static __device__ __forceinline__ short f2bf(float f) {
    union { float f; unsigned u; } v; v.f = f;
    unsigned r = v.u + 0x7fffu + ((v.u >> 16) & 1u);
    return (short)(r >> 16);
}

static __device__ __forceinline__ float fast_exp2(float x) {
    float r;
    asm("v_exp_f32 %0, %1" : "=v"(r) : "v"(x));
    return r;
}

#define GLD_LDS16(g, l) __builtin_amdgcn_global_load_lds( \
    (const __attribute__((address_space(1))) void*)(g),   \
    (__attribute__((address_space(3))) void*)(l), 16, 0, 0)

// Q pre-scale: (1/32) * log2(e) — folds softmax scale AND exp->exp2 conversion
#define QSCALE 0.04508422f

// ---------------------------------------------------------------------------
// pack_x (round-5 exact)
// ---------------------------------------------------------------------------
__global__ void pack_x(const float* __restrict__ x, short* __restrict__ xb) {
    int t = blockIdx.x * blockDim.x + threadIdx.x;
    const float* src = x + (size_t)t * 8;
    float4 v0 = *(const float4*)src;
    float4 v1 = *(const float4*)(src + 4);
    bf16x8 o;
    o[0] = f2bf(v0.x); o[1] = f2bf(v0.y); o[2] = f2bf(v0.z); o[3] = f2bf(v0.w);
    o[4] = f2bf(v1.x); o[5] = f2bf(v1.y); o[6] = f2bf(v1.z); o[7] = f2bf(v1.w);
    *(bf16x8*)(xb + (size_t)t * 8) = o;
}

// ---------------------------------------------------------------------------
// pack_wqkv2 / pack_wproj2 (round-12 exact, coalesced LDS-transpose)
// ---------------------------------------------------------------------------
__global__ void pack_wqkv2(const float* __restrict__ wq, const float* __restrict__ wk,
                           const float* __restrict__ wv, short* __restrict__ out) {
    __shared__ short tile[64][72];
    const int qh = blockIdx.y;
    const int qkv = qh >> 4, h = qh & 15;
    const int c0 = blockIdx.x * 64;
    const float* w = ((qkv == 0) ? wq : (qkv == 1) ? wk : wv) + (size_t)h * (C_ * D_);
    const int t = threadIdx.x;
    const int r = t >> 2;
    const int dc = (t & 3) * 16;

    const float* src = w + (size_t)(c0 + r) * D_ + dc;
#pragma unroll
    for (int j = 0; j < 4; ++j) {
        float4 v = *(const float4*)(src + j * 4);
        short4v s;
        s[0] = f2bf(v.x); s[1] = f2bf(v.y); s[2] = f2bf(v.z); s[3] = f2bf(v.w);
        *(short4v*)&tile[r][dc + j * 4] = s;
    }
    __syncthreads();

    const int d = t >> 2;
    const int cc = (t & 3) * 16;
    bf16x8 o0, o1;
#pragma unroll
    for (int j = 0; j < 8; ++j) {
        o0[j] = tile[cc + j][d];
        o1[j] = tile[cc + 8 + j][d];
    }
    short* dst = out + ((size_t)qkv * 1024 + h * 64 + d) * C_ + c0 + cc;
    *(bf16x8*)dst = o0;
    *(bf16x8*)(dst + 8) = o1;
}

__global__ void pack_wproj2(const float* __restrict__ wp, short* __restrict__ out) {
    __shared__ short tile[64][72];
    const int c0 = blockIdx.x * 64;
    const int n0 = blockIdx.y * 64;
    const int t = threadIdx.x;
    const int r = t >> 2;
    const int nc = (t & 3) * 16;

    const float* src = wp + (size_t)(c0 + r) * C_ + n0 + nc;
#pragma unroll
    for (int j = 0; j < 4; ++j) {
        float4 v = *(const float4*)(src + j * 4);
        short4v s;
        s[0] = f2bf(v.x); s[1] = f2bf(v.y); s[2] = f2bf(v.z); s[3] = f2bf(v.w);
        *(short4v*)&tile[r][nc + j * 4] = s;
    }
    __syncthreads();

    const int n = t >> 2;
    const int cc = (t & 3) * 16;
    bf16x8 o0, o1;
#pragma unroll
    for (int j = 0; j < 8; ++j) {
        o0[j] = tile[cc + j][n];
        o1[j] = tile[cc + 8 + j][n];
    }
    short* dst = out + (size_t)(n0 + n) * C_ + c0 + cc;
    *(bf16x8*)dst = o0;
    *(bf16x8*)(dst + 8) = o1;
}

// ---------------------------------------------------------------------------
// GEMM (m97 structure). MODE 1: fp32 out + bias.
// MODE 2: bf16 out; Q columns (col<1024) pre-scaled by QSCALE.
// ---------------------------------------------------------------------------
template<int MODE>
__global__ __launch_bounds__(256)
void gemm_lds(const short* __restrict__ A, const short* __restrict__ Bt,
              void* __restrict__ Cptr, const float* __restrict__ bias,
              int M, int N, int K) {
    __shared__ short As[128 * 32];
    __shared__ short Bs[128 * 32];
    const int tid = threadIdx.x;
    const int lane = tid & 63, wid = tid >> 6;
    const int wr = wid >> 1, wc = wid & 1;
    const int l15 = lane & 15, l4 = lane >> 4;
    const int m0 = blockIdx.y * 128, n0 = blockIdx.x * 128;

    f32x4 acc[4][4] = {};

    for (int k0 = 0; k0 < K; k0 += 32) {
#pragma unroll
        for (int p = 0; p < 2; ++p) {
            int e = p * 256 + tid;
            int r = e >> 2, c = e & 3;
            GLD_LDS16(A  + (size_t)(m0 + r) * K + k0 + c * 8, As + e * 8);
            GLD_LDS16(Bt + (size_t)(n0 + r) * K + k0 + c * 8, Bs + e * 8);
        }
        __syncthreads();
        bf16x8 af[4], bfr[4];
#pragma unroll
        for (int m = 0; m < 4; ++m)
            af[m] = *(const bf16x8*)(As + (wr * 64 + m * 16 + l15) * 32 + l4 * 8);
#pragma unroll
        for (int n = 0; n < 4; ++n)
            bfr[n] = *(const bf16x8*)(Bs + (wc * 64 + n * 16 + l15) * 32 + l4 * 8);
#pragma unroll
        for (int m = 0; m < 4; ++m)
#pragma unroll
            for (int n = 0; n < 4; ++n)
                acc[m][n] = __builtin_amdgcn_mfma_f32_16x16x32_bf16(af[m], bfr[n], acc[m][n], 0, 0, 0);
        __syncthreads();
    }

#pragma unroll
    for (int m = 0; m < 4; ++m) {
        int row_base = m0 + wr * 64 + m * 16 + l4 * 4;
#pragma unroll
        for (int n = 0; n < 4; ++n) {
            int col = n0 + wc * 64 + n * 16 + l15;
#pragma unroll
            for (int r = 0; r < 4; ++r) {
                int row = row_base + r;
                float v = acc[m][n][r];
                if (MODE == 1) {
                    ((float*)Cptr)[(size_t)row * N + col] = v + bias[col];
                } else {
                    if (col < 1024) v *= QSCALE;   // Q pre-scale
                    ((short*)Cptr)[(size_t)row * N + col] = f2bf(v);
                }
            }
        }
    }
}

// ---------------------------------------------------------------------------
// Flash attention v14 = v13 math (exp2 softmax, defer-max, v5 layouts) with
// PAIR-TILE processing: two KV tiles per barrier pair (2 barriers / 2 tiles),
// double-MLP V gather, PV(t) overlapped with QK^T(t+1). Ps slot reused within
// a wave (DS ops are in-order per wave; lgkmcnt(0) before each Ps readback).
// ---------------------------------------------------------------------------
__device__ __forceinline__ void softmax_phase(
    f32x4 S[4], f32x4 O[4], float* mrow, float* srow,
    int qrow0, int s0, bool diag, int l15, int l4, short* ps) {
    float pmax[4];
#pragma unroll
    for (int r = 0; r < 4; ++r) pmax[r] = -1e30f;
#pragma unroll
    for (int n = 0; n < 4; ++n) {
#pragma unroll
        for (int r = 0; r < 4; ++r) {
            float v = S[n][r];   // already scaled + in log2 domain
            if (diag) {
                int scol = s0 + n * 16 + l15;
                if (scol > qrow0 + r) v = -1e30f;
            }
            S[n][r] = v;
            pmax[r] = fmaxf(pmax[r], v);
        }
    }
#pragma unroll
    for (int r = 0; r < 4; ++r) {
        float v = pmax[r];
        v = fmaxf(v, __shfl_xor(v, 1));
        v = fmaxf(v, __shfl_xor(v, 2));
        v = fmaxf(v, __shfl_xor(v, 4));
        v = fmaxf(v, __shfl_xor(v, 8));
        pmax[r] = v;
    }
    // defer-max: skip O/s rescale while max growth <= 8 (P bounded by 2^8)
    int ok = (pmax[0] <= mrow[0] + 8.0f) & (pmax[1] <= mrow[1] + 8.0f) &
             (pmax[2] <= mrow[2] + 8.0f) & (pmax[3] <= mrow[3] + 8.0f);
    if (!__all(ok)) {
#pragma unroll
        for (int r = 0; r < 4; ++r) {
            float mnew = fmaxf(mrow[r], pmax[r]);
            float fr = fast_exp2(mrow[r] - mnew);
            mrow[r] = mnew;
            srow[r] *= fr;
#pragma unroll
            for (int n = 0; n < 4; ++n) O[n][r] *= fr;
        }
    }
    float psum[4];
#pragma unroll
    for (int r = 0; r < 4; ++r) psum[r] = 0.0f;
#pragma unroll
    for (int n = 0; n < 4; ++n) {
#pragma unroll
        for (int r = 0; r < 4; ++r) {
            float p = fast_exp2(S[n][r] - mrow[r]);
            psum[r] += p;
            ps[(l4 * 4 + r) * 72 + n * 16 + l15] = f2bf(p);
        }
    }
#pragma unroll
    for (int r = 0; r < 4; ++r) {
        float v = psum[r];
        v += __shfl_xor(v, 1);
        v += __shfl_xor(v, 2);
        v += __shfl_xor(v, 4);
        v += __shfl_xor(v, 8);
        srow[r] += v;
    }
}

__global__ __launch_bounds__(256)
void attn_v14(const short* __restrict__ qkv, short* __restrict__ out) {
    const int pi = blockIdx.x;        // 0..15  (strip pair)
    const int bh = blockIdx.y;        // 0..63
    const int b = bh >> 4;
    const int h = bh & 15;
    const int qA0 = pi * 64;
    const int qB0 = (31 - pi) * 64;
    const int ntA = pi + 1;
    const int ntB = 32 - pi;
    const int tid = threadIdx.x;
    const int wave = tid >> 6;
    const int lane = tid & 63;
    const int l15 = lane & 15, l4 = lane >> 4;

    __shared__ short Vt[2][64][72];     // two tiles' V^T (v5 per-tile layout)
    __shared__ short Ps[4][2][16][72];  // per-wave, per-strip P buffer (reused per tile)

    const size_t rs = 3 * C_;
    const short* qbA = qkv + ((size_t)b * T_ + qA0) * rs + h * 64;
    const short* qbB = qkv + ((size_t)b * T_ + qB0) * rs + h * 64;
    const short* kb  = qkv + (size_t)b * T_ * rs + C_ + h * 64;
    const short* vb  = qkv + (size_t)b * T_ * rs + 2 * C_ + h * 64;

    bf16x8 aqA0 = *(const bf16x8*)(qbA + (size_t)(wave * 16 + l15) * rs + l4 * 8);
    bf16x8 aqA1 = *(const bf16x8*)(qbA + (size_t)(wave * 16 + l15) * rs + 32 + l4 * 8);
    bf16x8 aqB0 = *(const bf16x8*)(qbB + (size_t)(wave * 16 + l15) * rs + l4 * 8);
    bf16x8 aqB1 = *(const bf16x8*)(qbB + (size_t)(wave * 16 + l15) * rs + 32 + l4 * 8);

    f32x4 OA[4] = {}, OB[4] = {};
    float mA[4], sA[4], mB[4], sB[4];
#pragma unroll
    for (int r = 0; r < 4; ++r) { mA[r] = mB[r] = -1e30f; sA[r] = sB[r] = 0.0f; }

    short* psB = &Ps[wave][0][0][0];
    short* psA = &Ps[wave][1][0][0];
    const int qrB = qB0 + wave * 16 + l4 * 4;
    const int qrA = qA0 + wave * 16 + l4 * 4;

    // one sub-tile: K frags -> QK^T -> softmax for both strips (Ps written)
    auto qk_sm = [&](int s0, bool actA) {
        bf16x8 bk0[4], bk1[4];
#pragma unroll
        for (int n = 0; n < 4; ++n) {
            const short* kr = kb + (size_t)(s0 + n * 16 + l15) * rs;
            bk0[n] = *(const bf16x8*)(kr + l4 * 8);
            bk1[n] = *(const bf16x8*)(kr + 32 + l4 * 8);
        }
        f32x4 S[4];
#pragma unroll
        for (int n = 0; n < 4; ++n) {
            f32x4 z = {};
            z = __builtin_amdgcn_mfma_f32_16x16x32_bf16(aqB0, bk0[n], z, 0, 0, 0);
            S[n] = __builtin_amdgcn_mfma_f32_16x16x32_bf16(aqB1, bk1[n], z, 0, 0, 0);
        }
        softmax_phase(S, OB, mB, sB, qrB, s0, s0 == qB0, l15, l4, psB);
        if (actA) {
            f32x4 SA[4];
#pragma unroll
            for (int n = 0; n < 4; ++n) {
                f32x4 z = {};
                z = __builtin_amdgcn_mfma_f32_16x16x32_bf16(aqA0, bk0[n], z, 0, 0, 0);
                SA[n] = __builtin_amdgcn_mfma_f32_16x16x32_bf16(aqA1, bk1[n], z, 0, 0, 0);
            }
            softmax_phase(SA, OA, mA, sA, qrA, s0, s0 == qA0, l15, l4, psA);
        }
    };

    // PV accumulate from Vt[slot] using current Ps contents
    auto pv = [&](int slot, bool actA) {
        bf16x8 apB0 = *(const bf16x8*)(psB + l15 * 72 + l4 * 8);
        bf16x8 apB1 = *(const bf16x8*)(psB + l15 * 72 + 32 + l4 * 8);
#pragma unroll
        for (int n = 0; n < 4; ++n) {
            bf16x8 bv0 = *(const bf16x8*)&Vt[slot][n * 16 + l15][l4 * 8];
            bf16x8 bv1 = *(const bf16x8*)&Vt[slot][n * 16 + l15][32 + l4 * 8];
            OB[n] = __builtin_amdgcn_mfma_f32_16x16x32_bf16(apB0, bv0, OB[n], 0, 0, 0);
            OB[n] = __builtin_amdgcn_mfma_f32_16x16x32_bf16(apB1, bv1, OB[n], 0, 0, 0);
        }
        if (actA) {
            bf16x8 apA0 = *(const bf16x8*)(psA + l15 * 72 + l4 * 8);
            bf16x8 apA1 = *(const bf16x8*)(psA + l15 * 72 + 32 + l4 * 8);
#pragma unroll
            for (int n = 0; n < 4; ++n) {
                bf16x8 bv0 = *(const bf16x8*)&Vt[slot][n * 16 + l15][l4 * 8];
                bf16x8 bv1 = *(const bf16x8*)&Vt[slot][n * 16 + l15][32 + l4 * 8];
                OA[n] = __builtin_amdgcn_mfma_f32_16x16x32_bf16(apA0, bv0, OA[n], 0, 0, 0);
                OA[n] = __builtin_amdgcn_mfma_f32_16x16x32_bf16(apA1, bv1, OA[n], 0, 0, 0);
            }
        }
    };

    const int npair = ntB & ~1;
    for (int t = 0; t < npair; t += 2) {
        const int s0 = t * 64;
        __syncthreads();  // both Vt slots free (all PV reads of prev pair done)

        // ---- stage V(t) and V(t+1): 2x MLP coalesced gather ----
#pragma unroll
        for (int p = 0; p < 2; ++p) {
            int e = p * 256 + tid;
            int d = e & 63, sc = e >> 6;
            bf16x8 v0, v1;
#pragma unroll
            for (int j = 0; j < 8; ++j) {
                v0[j] = vb[(size_t)(s0 + sc * 8 + j) * rs + d];
                v1[j] = vb[(size_t)(s0 + 64 + sc * 8 + j) * rs + d];
            }
            *(bf16x8*)&Vt[0][d][sc * 8] = v0;
            *(bf16x8*)&Vt[1][d][sc * 8] = v1;
        }

        // ---- sub-tile t: QK^T + softmax (overlaps V loads in flight) ----
        qk_sm(s0, t < ntA);

        __syncthreads();  // V(t), V(t+1) staged; Ps(t) drained

        // ---- PV(t) ∥ then sub-tile t+1 QK^T+softmax (independent chains) ----
        pv(0, t < ntA);
        qk_sm(s0 + 64, t + 1 < ntA);

        // wave-local: Ps(t+1) writes land before readback
        asm volatile("s_waitcnt lgkmcnt(0)" ::: "memory");
        __builtin_amdgcn_sched_barrier(0);

        pv(1, t + 1 < ntA);
    }

    if (ntB & 1) {  // odd tail: single tile, v5-style
        const int s0 = npair * 64;
        __syncthreads();
#pragma unroll
        for (int p = 0; p < 2; ++p) {
            int e = p * 256 + tid;
            int d = e & 63, sc = e >> 6;
            bf16x8 v0;
#pragma unroll
            for (int j = 0; j < 8; ++j)
                v0[j] = vb[(size_t)(s0 + sc * 8 + j) * rs + d];
            *(bf16x8*)&Vt[0][d][sc * 8] = v0;
        }
        qk_sm(s0, npair < ntA);
        __syncthreads();
        pv(0, npair < ntA);
    }

    // ---- normalize + store both strips ----
#pragma unroll
    for (int r = 0; r < 4; ++r) {
        int rowB = qB0 + wave * 16 + l4 * 4 + r;
        int rowA = qA0 + wave * 16 + l4 * 4 + r;
        float invB = 1.0f / sB[r];
        float invA = 1.0f / sA[r];
        size_t obB = ((size_t)b * T_ + rowB) * C_ + h * 64;
        size_t obA = ((size_t)b * T_ + rowA) * C_ + h * 64;
#pragma unroll
        for (int n = 0; n < 4; ++n) {
            out[obB + n * 16 + l15] = f2bf(OB[n][r] * invB);
            out[obA + n * 16 + l15] = f2bf(OA[n][r] * invA);
        }
    }
}

// ---------------------------------------------------------------------------
extern "C" void kernel_launch(void* const* d_in, const int* in_sizes, int n_in,
                              void* d_out, int out_size, void* d_ws, size_t ws_size,
                              hipStream_t stream) {
    const float* x     = (const float*)d_in[0];
    const float* wq    = (const float*)d_in[1];
    const float* wk    = (const float*)d_in[2];
    const float* wv    = (const float*)d_in[3];
    const float* wproj = (const float*)d_in[4];
    const float* bproj = (const float*)d_in[5];
    float* out = (float*)d_out;

    // workspace layout (shorts): wqkv_t | wproj_t | qkv | attn_b (also xb)
    short* wqkv_t  = (short*)d_ws;                  // 3072*1024
    short* wproj_t = wqkv_t + 3072 * 1024;          // 1024*1024
    short* qkv_b   = wproj_t + 1024 * 1024;         // 8192*3072
    short* attn_b  = qkv_b + (size_t)8192 * 3072;   // 8192*1024 (xb aliased here)
    short* xb      = attn_b;                        // x bf16, dead after gemm1
    // total = 75,497,472 bytes

    pack_x<<<4096, 256, 0, stream>>>(x, xb);
    pack_wqkv2<<<dim3(16, 48), 256, 0, stream>>>(wq, wk, wv, wqkv_t);
    pack_wproj2<<<dim3(16, 16), 256, 0, stream>>>(wproj, wproj_t);

    // QKV projection: [8192,1024] x [1024,3072] -> bf16 (Q cols pre-scaled)
    gemm_lds<2><<<dim3(24, 64), 256, 0, stream>>>(
        xb, wqkv_t, qkv_b, nullptr, 8192, 3072, 1024);

    // flash attention, causal-paired strips, pair-tile phases
    attn_v14<<<dim3(16, 64), 256, 0, stream>>>(qkv_b, attn_b);

    // output projection: [8192,1024] x [1024,1024] + bias -> fp32
    gemm_lds<1><<<dim3(8, 64), 256, 0, stream>>>(
        attn_b, wproj_t, out, bproj, 8192, 1024, 1024);
}

// Round 15
// 276.377 us; speedup vs baseline: 1.3431x; 1.0445x over previous
//
#include <hip/hip_runtime.h>
#include <hip/hip_bf16.h>
#include <stdint.h>

#define B_ 4
#define T_ 2048
#define C_ 1024
#define H_ 16
#define D_ 64

typedef __attribute__((ext_vector_type(8))) short bf16x8;
typedef __attribute__((ext_vector_type(4))) short short4v;
typedef __attribute__((ext_vector_type(4))) float f32x4;

static __device__ __forceinline__ short f2bf(float f) {
    union { float f; unsigned u; } v; v.f = f;
    unsigned r = v.u + 0x7fffu + ((v.u >> 16) & 1u);
    return (short)(r >> 16);
}

static __device__ __forceinline__ float fast_exp2(float x) {
    float r;
    asm("v_exp_f32 %0, %1" : "=v"(r) : "v"(x));
    return r;
}

#define GLD_LDS16(g, l) __builtin_amdgcn_global_load_lds( \
    (const __attribute__((address_space(1))) void*)(g),   \
    (__attribute__((address_space(3))) void*)(l), 16, 0, 0)

// Q pre-scale: (1/32) * log2(e) — folds softmax scale AND exp->exp2 conversion
#define QSCALE 0.04508422f

// ---------------------------------------------------------------------------
// pack_x (round-5 exact)
// ---------------------------------------------------------------------------
__global__ void pack_x(const float* __restrict__ x, short* __restrict__ xb) {
    int t = blockIdx.x * blockDim.x + threadIdx.x;
    const float* src = x + (size_t)t * 8;
    float4 v0 = *(const float4*)src;
    float4 v1 = *(const float4*)(src + 4);
    bf16x8 o;
    o[0] = f2bf(v0.x); o[1] = f2bf(v0.y); o[2] = f2bf(v0.z); o[3] = f2bf(v0.w);
    o[4] = f2bf(v1.x); o[5] = f2bf(v1.y); o[6] = f2bf(v1.z); o[7] = f2bf(v1.w);
    *(bf16x8*)(xb + (size_t)t * 8) = o;
}

// ---------------------------------------------------------------------------
// pack_wqkv2 / pack_wproj2 (round-12 exact, coalesced LDS-transpose)
// ---------------------------------------------------------------------------
__global__ void pack_wqkv2(const float* __restrict__ wq, const float* __restrict__ wk,
                           const float* __restrict__ wv, short* __restrict__ out) {
    __shared__ short tile[64][72];
    const int qh = blockIdx.y;
    const int qkv = qh >> 4, h = qh & 15;
    const int c0 = blockIdx.x * 64;
    const float* w = ((qkv == 0) ? wq : (qkv == 1) ? wk : wv) + (size_t)h * (C_ * D_);
    const int t = threadIdx.x;
    const int r = t >> 2;
    const int dc = (t & 3) * 16;

    const float* src = w + (size_t)(c0 + r) * D_ + dc;
#pragma unroll
    for (int j = 0; j < 4; ++j) {
        float4 v = *(const float4*)(src + j * 4);
        short4v s;
        s[0] = f2bf(v.x); s[1] = f2bf(v.y); s[2] = f2bf(v.z); s[3] = f2bf(v.w);
        *(short4v*)&tile[r][dc + j * 4] = s;
    }
    __syncthreads();

    const int d = t >> 2;
    const int cc = (t & 3) * 16;
    bf16x8 o0, o1;
#pragma unroll
    for (int j = 0; j < 8; ++j) {
        o0[j] = tile[cc + j][d];
        o1[j] = tile[cc + 8 + j][d];
    }
    short* dst = out + ((size_t)qkv * 1024 + h * 64 + d) * C_ + c0 + cc;
    *(bf16x8*)dst = o0;
    *(bf16x8*)(dst + 8) = o1;
}

__global__ void pack_wproj2(const float* __restrict__ wp, short* __restrict__ out) {
    __shared__ short tile[64][72];
    const int c0 = blockIdx.x * 64;
    const int n0 = blockIdx.y * 64;
    const int t = threadIdx.x;
    const int r = t >> 2;
    const int nc = (t & 3) * 16;

    const float* src = wp + (size_t)(c0 + r) * C_ + n0 + nc;
#pragma unroll
    for (int j = 0; j < 4; ++j) {
        float4 v = *(const float4*)(src + j * 4);
        short4v s;
        s[0] = f2bf(v.x); s[1] = f2bf(v.y); s[2] = f2bf(v.z); s[3] = f2bf(v.w);
        *(short4v*)&tile[r][nc + j * 4] = s;
    }
    __syncthreads();

    const int n = t >> 2;
    const int cc = (t & 3) * 16;
    bf16x8 o0, o1;
#pragma unroll
    for (int j = 0; j < 8; ++j) {
        o0[j] = tile[cc + j][n];
        o1[j] = tile[cc + 8 + j][n];
    }
    short* dst = out + (size_t)(n0 + n) * C_ + c0 + cc;
    *(bf16x8*)dst = o0;
    *(bf16x8*)(dst + 8) = o1;
}

// ---------------------------------------------------------------------------
// GEMM v15: m97 structure with BK=64 (half the barrier-drain events, 2x MFMA
// per drain) + chunk-XOR anti-bank-conflict swizzle (both-sides, rule #21):
//   LDS physical chunk pc at row r holds logical k-chunk lc = pc ^ (r&7);
//   global_load_lds dest stays LINEAR (hardware requirement); the global
//   SOURCE address carries the permutation; ds_read applies the same XOR.
//   64 lanes -> 8 lanes per bank-quad = LDS minimum -> conflict-free.
// MODE 1: fp32 out + bias. MODE 2: bf16 out, Q cols pre-scaled by QSCALE.
// ---------------------------------------------------------------------------
template<int MODE>
__global__ __launch_bounds__(256)
void gemm_lds(const short* __restrict__ A, const short* __restrict__ Bt,
              void* __restrict__ Cptr, const float* __restrict__ bias,
              int M, int N, int K) {
    __shared__ short As[128 * 64];
    __shared__ short Bs[128 * 64];
    const int tid = threadIdx.x;
    const int lane = tid & 63, wid = tid >> 6;
    const int wr = wid >> 1, wc = wid & 1;
    const int l15 = lane & 15, l4 = lane >> 4;
    const int m0 = blockIdx.y * 128, n0 = blockIdx.x * 128;

    f32x4 acc[4][4] = {};

    for (int k0 = 0; k0 < K; k0 += 64) {
        // ---- stage 128x64 A and B tiles: linear LDS dest, swizzled source ----
#pragma unroll
        for (int p = 0; p < 4; ++p) {
            int e = p * 256 + tid;
            int r = e >> 3, pc = e & 7;
            int lc = pc ^ (r & 7);   // logical 16B k-chunk this slot holds
            GLD_LDS16(A  + (size_t)(m0 + r) * K + k0 + lc * 8, As + e * 8);
            GLD_LDS16(Bt + (size_t)(n0 + r) * K + k0 + lc * 8, Bs + e * 8);
        }
        __syncthreads();

        // ---- two K-halves sequentially (keeps frag VGPR at BK=32 level) ----
#pragma unroll
        for (int kk = 0; kk < 2; ++kk) {
            bf16x8 af[4], bfr[4];
#pragma unroll
            for (int m = 0; m < 4; ++m) {
                int row = wr * 64 + m * 16 + l15;
                int pc = (kk * 4 + l4) ^ (row & 7);
                af[m] = *(const bf16x8*)(As + row * 64 + pc * 8);
            }
#pragma unroll
            for (int n = 0; n < 4; ++n) {
                int row = wc * 64 + n * 16 + l15;
                int pc = (kk * 4 + l4) ^ (row & 7);
                bfr[n] = *(const bf16x8*)(Bs + row * 64 + pc * 8);
            }
#pragma unroll
            for (int m = 0; m < 4; ++m)
#pragma unroll
                for (int n = 0; n < 4; ++n)
                    acc[m][n] = __builtin_amdgcn_mfma_f32_16x16x32_bf16(af[m], bfr[n], acc[m][n], 0, 0, 0);
        }
        __syncthreads();
    }

#pragma unroll
    for (int m = 0; m < 4; ++m) {
        int row_base = m0 + wr * 64 + m * 16 + l4 * 4;
#pragma unroll
        for (int n = 0; n < 4; ++n) {
            int col = n0 + wc * 64 + n * 16 + l15;
#pragma unroll
            for (int r = 0; r < 4; ++r) {
                int row = row_base + r;
                float v = acc[m][n][r];
                if (MODE == 1) {
                    ((float*)Cptr)[(size_t)row * N + col] = v + bias[col];
                } else {
                    if (col < 1024) v *= QSCALE;   // Q pre-scale
                    ((short*)Cptr)[(size_t)row * N + col] = f2bf(v);
                }
            }
        }
    }
}

// ---------------------------------------------------------------------------
// Flash attention v14 (round-14 exact — pair-tile phases, exp2 softmax,
// defer-max, v5 layouts). Frozen.
// ---------------------------------------------------------------------------
__device__ __forceinline__ void softmax_phase(
    f32x4 S[4], f32x4 O[4], float* mrow, float* srow,
    int qrow0, int s0, bool diag, int l15, int l4, short* ps) {
    float pmax[4];
#pragma unroll
    for (int r = 0; r < 4; ++r) pmax[r] = -1e30f;
#pragma unroll
    for (int n = 0; n < 4; ++n) {
#pragma unroll
        for (int r = 0; r < 4; ++r) {
            float v = S[n][r];   // already scaled + in log2 domain
            if (diag) {
                int scol = s0 + n * 16 + l15;
                if (scol > qrow0 + r) v = -1e30f;
            }
            S[n][r] = v;
            pmax[r] = fmaxf(pmax[r], v);
        }
    }
#pragma unroll
    for (int r = 0; r < 4; ++r) {
        float v = pmax[r];
        v = fmaxf(v, __shfl_xor(v, 1));
        v = fmaxf(v, __shfl_xor(v, 2));
        v = fmaxf(v, __shfl_xor(v, 4));
        v = fmaxf(v, __shfl_xor(v, 8));
        pmax[r] = v;
    }
    // defer-max: skip O/s rescale while max growth <= 8 (P bounded by 2^8)
    int ok = (pmax[0] <= mrow[0] + 8.0f) & (pmax[1] <= mrow[1] + 8.0f) &
             (pmax[2] <= mrow[2] + 8.0f) & (pmax[3] <= mrow[3] + 8.0f);
    if (!__all(ok)) {
#pragma unroll
        for (int r = 0; r < 4; ++r) {
            float mnew = fmaxf(mrow[r], pmax[r]);
            float fr = fast_exp2(mrow[r] - mnew);
            mrow[r] = mnew;
            srow[r] *= fr;
#pragma unroll
            for (int n = 0; n < 4; ++n) O[n][r] *= fr;
        }
    }
    float psum[4];
#pragma unroll
    for (int r = 0; r < 4; ++r) psum[r] = 0.0f;
#pragma unroll
    for (int n = 0; n < 4; ++n) {
#pragma unroll
        for (int r = 0; r < 4; ++r) {
            float p = fast_exp2(S[n][r] - mrow[r]);
            psum[r] += p;
            ps[(l4 * 4 + r) * 72 + n * 16 + l15] = f2bf(p);
        }
    }
#pragma unroll
    for (int r = 0; r < 4; ++r) {
        float v = psum[r];
        v += __shfl_xor(v, 1);
        v += __shfl_xor(v, 2);
        v += __shfl_xor(v, 4);
        v += __shfl_xor(v, 8);
        srow[r] += v;
    }
}

__global__ __launch_bounds__(256)
void attn_v14(const short* __restrict__ qkv, short* __restrict__ out) {
    const int pi = blockIdx.x;        // 0..15  (strip pair)
    const int bh = blockIdx.y;        // 0..63
    const int b = bh >> 4;
    const int h = bh & 15;
    const int qA0 = pi * 64;
    const int qB0 = (31 - pi) * 64;
    const int ntA = pi + 1;
    const int ntB = 32 - pi;
    const int tid = threadIdx.x;
    const int wave = tid >> 6;
    const int lane = tid & 63;
    const int l15 = lane & 15, l4 = lane >> 4;

    __shared__ short Vt[2][64][72];     // two tiles' V^T (v5 per-tile layout)
    __shared__ short Ps[4][2][16][72];  // per-wave, per-strip P buffer (reused per tile)

    const size_t rs = 3 * C_;
    const short* qbA = qkv + ((size_t)b * T_ + qA0) * rs + h * 64;
    const short* qbB = qkv + ((size_t)b * T_ + qB0) * rs + h * 64;
    const short* kb  = qkv + (size_t)b * T_ * rs + C_ + h * 64;
    const short* vb  = qkv + (size_t)b * T_ * rs + 2 * C_ + h * 64;

    bf16x8 aqA0 = *(const bf16x8*)(qbA + (size_t)(wave * 16 + l15) * rs + l4 * 8);
    bf16x8 aqA1 = *(const bf16x8*)(qbA + (size_t)(wave * 16 + l15) * rs + 32 + l4 * 8);
    bf16x8 aqB0 = *(const bf16x8*)(qbB + (size_t)(wave * 16 + l15) * rs + l4 * 8);
    bf16x8 aqB1 = *(const bf16x8*)(qbB + (size_t)(wave * 16 + l15) * rs + 32 + l4 * 8);

    f32x4 OA[4] = {}, OB[4] = {};
    float mA[4], sA[4], mB[4], sB[4];
#pragma unroll
    for (int r = 0; r < 4; ++r) { mA[r] = mB[r] = -1e30f; sA[r] = sB[r] = 0.0f; }

    short* psB = &Ps[wave][0][0][0];
    short* psA = &Ps[wave][1][0][0];
    const int qrB = qB0 + wave * 16 + l4 * 4;
    const int qrA = qA0 + wave * 16 + l4 * 4;

    auto qk_sm = [&](int s0, bool actA) {
        bf16x8 bk0[4], bk1[4];
#pragma unroll
        for (int n = 0; n < 4; ++n) {
            const short* kr = kb + (size_t)(s0 + n * 16 + l15) * rs;
            bk0[n] = *(const bf16x8*)(kr + l4 * 8);
            bk1[n] = *(const bf16x8*)(kr + 32 + l4 * 8);
        }
        f32x4 S[4];
#pragma unroll
        for (int n = 0; n < 4; ++n) {
            f32x4 z = {};
            z = __builtin_amdgcn_mfma_f32_16x16x32_bf16(aqB0, bk0[n], z, 0, 0, 0);
            S[n] = __builtin_amdgcn_mfma_f32_16x16x32_bf16(aqB1, bk1[n], z, 0, 0, 0);
        }
        softmax_phase(S, OB, mB, sB, qrB, s0, s0 == qB0, l15, l4, psB);
        if (actA) {
            f32x4 SA[4];
#pragma unroll
            for (int n = 0; n < 4; ++n) {
                f32x4 z = {};
                z = __builtin_amdgcn_mfma_f32_16x16x32_bf16(aqA0, bk0[n], z, 0, 0, 0);
                SA[n] = __builtin_amdgcn_mfma_f32_16x16x32_bf16(aqA1, bk1[n], z, 0, 0, 0);
            }
            softmax_phase(SA, OA, mA, sA, qrA, s0, s0 == qA0, l15, l4, psA);
        }
    };

    auto pv = [&](int slot, bool actA) {
        bf16x8 apB0 = *(const bf16x8*)(psB + l15 * 72 + l4 * 8);
        bf16x8 apB1 = *(const bf16x8*)(psB + l15 * 72 + 32 + l4 * 8);
#pragma unroll
        for (int n = 0; n < 4; ++n) {
            bf16x8 bv0 = *(const bf16x8*)&Vt[slot][n * 16 + l15][l4 * 8];
            bf16x8 bv1 = *(const bf16x8*)&Vt[slot][n * 16 + l15][32 + l4 * 8];
            OB[n] = __builtin_amdgcn_mfma_f32_16x16x32_bf16(apB0, bv0, OB[n], 0, 0, 0);
            OB[n] = __builtin_amdgcn_mfma_f32_16x16x32_bf16(apB1, bv1, OB[n], 0, 0, 0);
        }
        if (actA) {
            bf16x8 apA0 = *(const bf16x8*)(psA + l15 * 72 + l4 * 8);
            bf16x8 apA1 = *(const bf16x8*)(psA + l15 * 72 + 32 + l4 * 8);
#pragma unroll
            for (int n = 0; n < 4; ++n) {
                bf16x8 bv0 = *(const bf16x8*)&Vt[slot][n * 16 + l15][l4 * 8];
                bf16x8 bv1 = *(const bf16x8*)&Vt[slot][n * 16 + l15][32 + l4 * 8];
                OA[n] = __builtin_amdgcn_mfma_f32_16x16x32_bf16(apA0, bv0, OA[n], 0, 0, 0);
                OA[n] = __builtin_amdgcn_mfma_f32_16x16x32_bf16(apA1, bv1, OA[n], 0, 0, 0);
            }
        }
    };

    const int npair = ntB & ~1;
    for (int t = 0; t < npair; t += 2) {
        const int s0 = t * 64;
        __syncthreads();  // both Vt slots free (all PV reads of prev pair done)

        // ---- stage V(t) and V(t+1): 2x MLP coalesced gather ----
#pragma unroll
        for (int p = 0; p < 2; ++p) {
            int e = p * 256 + tid;
            int d = e & 63, sc = e >> 6;
            bf16x8 v0, v1;
#pragma unroll
            for (int j = 0; j < 8; ++j) {
                v0[j] = vb[(size_t)(s0 + sc * 8 + j) * rs + d];
                v1[j] = vb[(size_t)(s0 + 64 + sc * 8 + j) * rs + d];
            }
            *(bf16x8*)&Vt[0][d][sc * 8] = v0;
            *(bf16x8*)&Vt[1][d][sc * 8] = v1;
        }

        qk_sm(s0, t < ntA);

        __syncthreads();  // V(t), V(t+1) staged; Ps(t) drained

        pv(0, t < ntA);
        qk_sm(s0 + 64, t + 1 < ntA);

        asm volatile("s_waitcnt lgkmcnt(0)" ::: "memory");
        __builtin_amdgcn_sched_barrier(0);

        pv(1, t + 1 < ntA);
    }

    if (ntB & 1) {  // odd tail: single tile, v5-style
        const int s0 = npair * 64;
        __syncthreads();
#pragma unroll
        for (int p = 0; p < 2; ++p) {
            int e = p * 256 + tid;
            int d = e & 63, sc = e >> 6;
            bf16x8 v0;
#pragma unroll
            for (int j = 0; j < 8; ++j)
                v0[j] = vb[(size_t)(s0 + sc * 8 + j) * rs + d];
            *(bf16x8*)&Vt[0][d][sc * 8] = v0;
        }
        qk_sm(s0, npair < ntA);
        __syncthreads();
        pv(0, npair < ntA);
    }

    // ---- normalize + store both strips ----
#pragma unroll
    for (int r = 0; r < 4; ++r) {
        int rowB = qB0 + wave * 16 + l4 * 4 + r;
        int rowA = qA0 + wave * 16 + l4 * 4 + r;
        float invB = 1.0f / sB[r];
        float invA = 1.0f / sA[r];
        size_t obB = ((size_t)b * T_ + rowB) * C_ + h * 64;
        size_t obA = ((size_t)b * T_ + rowA) * C_ + h * 64;
#pragma unroll
        for (int n = 0; n < 4; ++n) {
            out[obB + n * 16 + l15] = f2bf(OB[n][r] * invB);
            out[obA + n * 16 + l15] = f2bf(OA[n][r] * invA);
        }
    }
}

// ---------------------------------------------------------------------------
extern "C" void kernel_launch(void* const* d_in, const int* in_sizes, int n_in,
                              void* d_out, int out_size, void* d_ws, size_t ws_size,
                              hipStream_t stream) {
    const float* x     = (const float*)d_in[0];
    const float* wq    = (const float*)d_in[1];
    const float* wk    = (const float*)d_in[2];
    const float* wv    = (const float*)d_in[3];
    const float* wproj = (const float*)d_in[4];
    const float* bproj = (const float*)d_in[5];
    float* out = (float*)d_out;

    // workspace layout (shorts): wqkv_t | wproj_t | qkv | attn_b (also xb)
    short* wqkv_t  = (short*)d_ws;                  // 3072*1024
    short* wproj_t = wqkv_t + 3072 * 1024;          // 1024*1024
    short* qkv_b   = wproj_t + 1024 * 1024;         // 8192*3072
    short* attn_b  = qkv_b + (size_t)8192 * 3072;   // 8192*1024 (xb aliased here)
    short* xb      = attn_b;                        // x bf16, dead after gemm1
    // total = 75,497,472 bytes

    pack_x<<<4096, 256, 0, stream>>>(x, xb);
    pack_wqkv2<<<dim3(16, 48), 256, 0, stream>>>(wq, wk, wv, wqkv_t);
    pack_wproj2<<<dim3(16, 16), 256, 0, stream>>>(wproj, wproj_t);

    // QKV projection: [8192,1024] x [1024,3072] -> bf16 (Q cols pre-scaled)
    gemm_lds<2><<<dim3(24, 64), 256, 0, stream>>>(
        xb, wqkv_t, qkv_b, nullptr, 8192, 3072, 1024);

    // flash attention, causal-paired strips, pair-tile phases (frozen)
    attn_v14<<<dim3(16, 64), 256, 0, stream>>>(qkv_b, attn_b);

    // output projection: [8192,1024] x [1024,1024] + bias -> fp32
    gemm_lds<1><<<dim3(8, 64), 256, 0, stream>>>(
        attn_b, wproj_t, out, bproj, 8192, 1024, 1024);
}

// Round 16
// 271.256 us; speedup vs baseline: 1.3684x; 1.0189x over previous
//
#include <hip/hip_runtime.h>
#include <hip/hip_bf16.h>
#include <stdint.h>

#define B_ 4
#define T_ 2048
#define C_ 1024
#define H_ 16
#define D_ 64

typedef __attribute__((ext_vector_type(8))) short bf16x8;
typedef __attribute__((ext_vector_type(4))) short short4v;
typedef __attribute__((ext_vector_type(4))) float f32x4;

static __device__ __forceinline__ short f2bf(float f) {
    union { float f; unsigned u; } v; v.f = f;
    unsigned r = v.u + 0x7fffu + ((v.u >> 16) & 1u);
    return (short)(r >> 16);
}

static __device__ __forceinline__ float fast_exp2(float x) {
    float r;
    asm("v_exp_f32 %0, %1" : "=v"(r) : "v"(x));
    return r;
}

#define GLD_LDS16(g, l) __builtin_amdgcn_global_load_lds( \
    (const __attribute__((address_space(1))) void*)(g),   \
    (__attribute__((address_space(3))) void*)(l), 16, 0, 0)

// Q pre-scale: (1/32) * log2(e) — folds softmax scale AND exp->exp2 conversion
#define QSCALE 0.04508422f

// ---------------------------------------------------------------------------
// pack_x (round-5 exact)
// ---------------------------------------------------------------------------
__global__ void pack_x(const float* __restrict__ x, short* __restrict__ xb) {
    int t = blockIdx.x * blockDim.x + threadIdx.x;
    const float* src = x + (size_t)t * 8;
    float4 v0 = *(const float4*)src;
    float4 v1 = *(const float4*)(src + 4);
    bf16x8 o;
    o[0] = f2bf(v0.x); o[1] = f2bf(v0.y); o[2] = f2bf(v0.z); o[3] = f2bf(v0.w);
    o[4] = f2bf(v1.x); o[5] = f2bf(v1.y); o[6] = f2bf(v1.z); o[7] = f2bf(v1.w);
    *(bf16x8*)(xb + (size_t)t * 8) = o;
}

// ---------------------------------------------------------------------------
// pack_wqkv2 / pack_wproj2 (round-12 exact, coalesced LDS-transpose)
// ---------------------------------------------------------------------------
__global__ void pack_wqkv2(const float* __restrict__ wq, const float* __restrict__ wk,
                           const float* __restrict__ wv, short* __restrict__ out) {
    __shared__ short tile[64][72];
    const int qh = blockIdx.y;
    const int qkv = qh >> 4, h = qh & 15;
    const int c0 = blockIdx.x * 64;
    const float* w = ((qkv == 0) ? wq : (qkv == 1) ? wk : wv) + (size_t)h * (C_ * D_);
    const int t = threadIdx.x;
    const int r = t >> 2;
    const int dc = (t & 3) * 16;

    const float* src = w + (size_t)(c0 + r) * D_ + dc;
#pragma unroll
    for (int j = 0; j < 4; ++j) {
        float4 v = *(const float4*)(src + j * 4);
        short4v s;
        s[0] = f2bf(v.x); s[1] = f2bf(v.y); s[2] = f2bf(v.z); s[3] = f2bf(v.w);
        *(short4v*)&tile[r][dc + j * 4] = s;
    }
    __syncthreads();

    const int d = t >> 2;
    const int cc = (t & 3) * 16;
    bf16x8 o0, o1;
#pragma unroll
    for (int j = 0; j < 8; ++j) {
        o0[j] = tile[cc + j][d];
        o1[j] = tile[cc + 8 + j][d];
    }
    short* dst = out + ((size_t)qkv * 1024 + h * 64 + d) * C_ + c0 + cc;
    *(bf16x8*)dst = o0;
    *(bf16x8*)(dst + 8) = o1;
}

__global__ void pack_wproj2(const float* __restrict__ wp, short* __restrict__ out) {
    __shared__ short tile[64][72];
    const int c0 = blockIdx.x * 64;
    const int n0 = blockIdx.y * 64;
    const int t = threadIdx.x;
    const int r = t >> 2;
    const int nc = (t & 3) * 16;

    const float* src = wp + (size_t)(c0 + r) * C_ + n0 + nc;
#pragma unroll
    for (int j = 0; j < 4; ++j) {
        float4 v = *(const float4*)(src + j * 4);
        short4v s;
        s[0] = f2bf(v.x); s[1] = f2bf(v.y); s[2] = f2bf(v.z); s[3] = f2bf(v.w);
        *(short4v*)&tile[r][nc + j * 4] = s;
    }
    __syncthreads();

    const int n = t >> 2;
    const int cc = (t & 3) * 16;
    bf16x8 o0, o1;
#pragma unroll
    for (int j = 0; j < 8; ++j) {
        o0[j] = tile[cc + j][n];
        o1[j] = tile[cc + 8 + j][n];
    }
    short* dst = out + (size_t)(n0 + n) * C_ + c0 + cc;
    *(bf16x8*)dst = o0;
    *(bf16x8*)(dst + 8) = o1;
}

// ---------------------------------------------------------------------------
// GEMM v15 (BK=64 + both-sides chunk-XOR, round-15 verified).
// MODE 1: fp32 out + bias.
// MODE 2: QKV split epilogue (v6-verified): Q (scaled) and K -> qk[row*2048],
//         V -> TRANSPOSED vt[(b*1024 + cm)*2048 + t] (4 t per lane, 8B store).
// ---------------------------------------------------------------------------
template<int MODE>
__global__ __launch_bounds__(256)
void gemm_lds(const short* __restrict__ A, const short* __restrict__ Bt,
              void* __restrict__ Cptr, short* __restrict__ vtptr,
              const float* __restrict__ bias, int M, int N, int K) {
    __shared__ short As[128 * 64];
    __shared__ short Bs[128 * 64];
    const int tid = threadIdx.x;
    const int lane = tid & 63, wid = tid >> 6;
    const int wr = wid >> 1, wc = wid & 1;
    const int l15 = lane & 15, l4 = lane >> 4;
    const int m0 = blockIdx.y * 128, n0 = blockIdx.x * 128;

    f32x4 acc[4][4] = {};

    for (int k0 = 0; k0 < K; k0 += 64) {
        // ---- stage 128x64 A and B tiles: linear LDS dest, swizzled source ----
#pragma unroll
        for (int p = 0; p < 4; ++p) {
            int e = p * 256 + tid;
            int r = e >> 3, pc = e & 7;
            int lc = pc ^ (r & 7);   // logical 16B k-chunk this slot holds
            GLD_LDS16(A  + (size_t)(m0 + r) * K + k0 + lc * 8, As + e * 8);
            GLD_LDS16(Bt + (size_t)(n0 + r) * K + k0 + lc * 8, Bs + e * 8);
        }
        __syncthreads();

        // ---- two K-halves sequentially ----
#pragma unroll
        for (int kk = 0; kk < 2; ++kk) {
            bf16x8 af[4], bfr[4];
#pragma unroll
            for (int m = 0; m < 4; ++m) {
                int row = wr * 64 + m * 16 + l15;
                int pc = (kk * 4 + l4) ^ (row & 7);
                af[m] = *(const bf16x8*)(As + row * 64 + pc * 8);
            }
#pragma unroll
            for (int n = 0; n < 4; ++n) {
                int row = wc * 64 + n * 16 + l15;
                int pc = (kk * 4 + l4) ^ (row & 7);
                bfr[n] = *(const bf16x8*)(Bs + row * 64 + pc * 8);
            }
#pragma unroll
            for (int m = 0; m < 4; ++m)
#pragma unroll
                for (int n = 0; n < 4; ++n)
                    acc[m][n] = __builtin_amdgcn_mfma_f32_16x16x32_bf16(af[m], bfr[n], acc[m][n], 0, 0, 0);
        }
        __syncthreads();
    }

#pragma unroll
    for (int m = 0; m < 4; ++m) {
        int row_base = m0 + wr * 64 + m * 16 + l4 * 4;
#pragma unroll
        for (int n = 0; n < 4; ++n) {
            int col = n0 + wc * 64 + n * 16 + l15;
            if (MODE == 1) {
#pragma unroll
                for (int r = 0; r < 4; ++r)
                    ((float*)Cptr)[(size_t)(row_base + r) * N + col] =
                        acc[m][n][r] + bias[col];
            } else {  // MODE 2
                if (col < 2048) {  // Q (scaled) | K -> qk rows of 2048
                    float q = (col < 1024) ? QSCALE : 1.0f;
#pragma unroll
                    for (int r = 0; r < 4; ++r)
                        ((short*)Cptr)[(size_t)(row_base + r) * 2048 + col] =
                            f2bf(acc[m][n][r] * q);
                } else {           // V: transposed scatter (v6-verified)
                    int cm = col - 2048;
                    int bq = row_base >> 11, t = row_base & 2047;
                    short4v s;
                    s[0] = f2bf(acc[m][n][0]); s[1] = f2bf(acc[m][n][1]);
                    s[2] = f2bf(acc[m][n][2]); s[3] = f2bf(acc[m][n][3]);
                    *(short4v*)(vtptr + ((size_t)bq * 1024 + cm) * 2048 + t) = s;
                }
            }
        }
    }
}

// ---------------------------------------------------------------------------
// Flash attention v16 = v14 structure (pair-tile phases, exp2 softmax,
// defer-max) with V staged via global_load_lds from the vt buffer:
//   - Vt[2][64][64] LINEAR dest (GLD requirement), chunk-XOR carried by the
//     global SOURCE address; ds_read applies the same XOR (rule #21).
//   - zero VALU / register round-trip in staging; GLD issued at pair top,
//     drained by the existing mid-pair barrier (latency hides under QK^T).
// Q/K from qk[8192][2048] (v6-verified addressing).
// ---------------------------------------------------------------------------
__device__ __forceinline__ void softmax_phase(
    f32x4 S[4], f32x4 O[4], float* mrow, float* srow,
    int qrow0, int s0, bool diag, int l15, int l4, short* ps) {
    float pmax[4];
#pragma unroll
    for (int r = 0; r < 4; ++r) pmax[r] = -1e30f;
#pragma unroll
    for (int n = 0; n < 4; ++n) {
#pragma unroll
        for (int r = 0; r < 4; ++r) {
            float v = S[n][r];   // already scaled + in log2 domain
            if (diag) {
                int scol = s0 + n * 16 + l15;
                if (scol > qrow0 + r) v = -1e30f;
            }
            S[n][r] = v;
            pmax[r] = fmaxf(pmax[r], v);
        }
    }
#pragma unroll
    for (int r = 0; r < 4; ++r) {
        float v = pmax[r];
        v = fmaxf(v, __shfl_xor(v, 1));
        v = fmaxf(v, __shfl_xor(v, 2));
        v = fmaxf(v, __shfl_xor(v, 4));
        v = fmaxf(v, __shfl_xor(v, 8));
        pmax[r] = v;
    }
    // defer-max: skip O/s rescale while max growth <= 8 (P bounded by 2^8)
    int ok = (pmax[0] <= mrow[0] + 8.0f) & (pmax[1] <= mrow[1] + 8.0f) &
             (pmax[2] <= mrow[2] + 8.0f) & (pmax[3] <= mrow[3] + 8.0f);
    if (!__all(ok)) {
#pragma unroll
        for (int r = 0; r < 4; ++r) {
            float mnew = fmaxf(mrow[r], pmax[r]);
            float fr = fast_exp2(mrow[r] - mnew);
            mrow[r] = mnew;
            srow[r] *= fr;
#pragma unroll
            for (int n = 0; n < 4; ++n) O[n][r] *= fr;
        }
    }
    float psum[4];
#pragma unroll
    for (int r = 0; r < 4; ++r) psum[r] = 0.0f;
#pragma unroll
    for (int n = 0; n < 4; ++n) {
#pragma unroll
        for (int r = 0; r < 4; ++r) {
            float p = fast_exp2(S[n][r] - mrow[r]);
            psum[r] += p;
            ps[(l4 * 4 + r) * 72 + n * 16 + l15] = f2bf(p);
        }
    }
#pragma unroll
    for (int r = 0; r < 4; ++r) {
        float v = psum[r];
        v += __shfl_xor(v, 1);
        v += __shfl_xor(v, 2);
        v += __shfl_xor(v, 4);
        v += __shfl_xor(v, 8);
        srow[r] += v;
    }
}

__global__ __launch_bounds__(256)
void attn_v16(const short* __restrict__ qk, const short* __restrict__ vt,
              short* __restrict__ out) {
    const int pi = blockIdx.x;        // 0..15  (strip pair)
    const int bh = blockIdx.y;        // 0..63
    const int b = bh >> 4;
    const int h = bh & 15;
    const int qA0 = pi * 64;
    const int qB0 = (31 - pi) * 64;
    const int ntA = pi + 1;
    const int ntB = 32 - pi;
    const int tid = threadIdx.x;
    const int wave = tid >> 6;
    const int lane = tid & 63;
    const int l15 = lane & 15, l4 = lane >> 4;

    __shared__ short Vt[2][64][64];     // linear (GLD dest); source-swizzled
    __shared__ short Ps[4][2][16][72];  // per-wave, per-strip P buffer

    const size_t rs = 2 * C_;  // 2048
    const short* qbA = qk + ((size_t)b * T_ + qA0) * rs + h * 64;
    const short* qbB = qk + ((size_t)b * T_ + qB0) * rs + h * 64;
    const short* kb  = qk + (size_t)b * T_ * rs + 1024 + h * 64;
    const short* vtb = vt + (size_t)bh * 64 * T_;   // V^T rows [d][t]

    bf16x8 aqA0 = *(const bf16x8*)(qbA + (size_t)(wave * 16 + l15) * rs + l4 * 8);
    bf16x8 aqA1 = *(const bf16x8*)(qbA + (size_t)(wave * 16 + l15) * rs + 32 + l4 * 8);
    bf16x8 aqB0 = *(const bf16x8*)(qbB + (size_t)(wave * 16 + l15) * rs + l4 * 8);
    bf16x8 aqB1 = *(const bf16x8*)(qbB + (size_t)(wave * 16 + l15) * rs + 32 + l4 * 8);

    f32x4 OA[4] = {}, OB[4] = {};
    float mA[4], sA[4], mB[4], sB[4];
#pragma unroll
    for (int r = 0; r < 4; ++r) { mA[r] = mB[r] = -1e30f; sA[r] = sB[r] = 0.0f; }

    short* psB = &Ps[wave][0][0][0];
    short* psA = &Ps[wave][1][0][0];
    const int qrB = qB0 + wave * 16 + l4 * 4;
    const int qrA = qA0 + wave * 16 + l4 * 4;

    // staging geometry: slot e covers row r=e>>3, physical chunk pc=e&7;
    // source column chunk lc = pc ^ (r&7)  (both-sides XOR swizzle)
    const int sr = tid >> 3;                 // row this thread covers (p=0)
    const int spc = tid & 7;

    auto stage = [&](int slot, int s0) {
#pragma unroll
        for (int p = 0; p < 2; ++p) {
            int e = p * 256 + tid;
            int r = (p == 0) ? sr : (sr + 32);
            int lc = spc ^ (r & 7);
            GLD_LDS16(vtb + (size_t)r * T_ + s0 + lc * 8,
                      &Vt[slot][0][0] + e * 8);
        }
    };

    auto qk_sm = [&](int s0, bool actA) {
        bf16x8 bk0[4], bk1[4];
#pragma unroll
        for (int n = 0; n < 4; ++n) {
            const short* kr = kb + (size_t)(s0 + n * 16 + l15) * rs;
            bk0[n] = *(const bf16x8*)(kr + l4 * 8);
            bk1[n] = *(const bf16x8*)(kr + 32 + l4 * 8);
        }
        f32x4 S[4];
#pragma unroll
        for (int n = 0; n < 4; ++n) {
            f32x4 z = {};
            z = __builtin_amdgcn_mfma_f32_16x16x32_bf16(aqB0, bk0[n], z, 0, 0, 0);
            S[n] = __builtin_amdgcn_mfma_f32_16x16x32_bf16(aqB1, bk1[n], z, 0, 0, 0);
        }
        softmax_phase(S, OB, mB, sB, qrB, s0, s0 == qB0, l15, l4, psB);
        if (actA) {
            f32x4 SA[4];
#pragma unroll
            for (int n = 0; n < 4; ++n) {
                f32x4 z = {};
                z = __builtin_amdgcn_mfma_f32_16x16x32_bf16(aqA0, bk0[n], z, 0, 0, 0);
                SA[n] = __builtin_amdgcn_mfma_f32_16x16x32_bf16(aqA1, bk1[n], z, 0, 0, 0);
            }
            softmax_phase(SA, OA, mA, sA, qrA, s0, s0 == qA0, l15, l4, psA);
        }
    };

    auto pv = [&](int slot, bool actA) {
        bf16x8 apB0 = *(const bf16x8*)(psB + l15 * 72 + l4 * 8);
        bf16x8 apB1 = *(const bf16x8*)(psB + l15 * 72 + 32 + l4 * 8);
        const int x7 = l15 & 7;
#pragma unroll
        for (int n = 0; n < 4; ++n) {
            const short* vrow = &Vt[slot][n * 16 + l15][0];
            bf16x8 bv0 = *(const bf16x8*)(vrow + ((l4 ^ x7) * 8));
            bf16x8 bv1 = *(const bf16x8*)(vrow + (((l4 + 4) ^ x7) * 8));
            OB[n] = __builtin_amdgcn_mfma_f32_16x16x32_bf16(apB0, bv0, OB[n], 0, 0, 0);
            OB[n] = __builtin_amdgcn_mfma_f32_16x16x32_bf16(apB1, bv1, OB[n], 0, 0, 0);
        }
        if (actA) {
            bf16x8 apA0 = *(const bf16x8*)(psA + l15 * 72 + l4 * 8);
            bf16x8 apA1 = *(const bf16x8*)(psA + l15 * 72 + 32 + l4 * 8);
#pragma unroll
            for (int n = 0; n < 4; ++n) {
                const short* vrow = &Vt[slot][n * 16 + l15][0];
                bf16x8 bv0 = *(const bf16x8*)(vrow + ((l4 ^ x7) * 8));
                bf16x8 bv1 = *(const bf16x8*)(vrow + (((l4 + 4) ^ x7) * 8));
                OA[n] = __builtin_amdgcn_mfma_f32_16x16x32_bf16(apA0, bv0, OA[n], 0, 0, 0);
                OA[n] = __builtin_amdgcn_mfma_f32_16x16x32_bf16(apA1, bv1, OA[n], 0, 0, 0);
            }
        }
    };

    const int npair = ntB & ~1;
    for (int t = 0; t < npair; t += 2) {
        const int s0 = t * 64;
        __syncthreads();  // both Vt slots free (all PV reads of prev pair done)

        // ---- issue V(t), V(t+1) via global_load_lds (fire-and-forget) ----
        stage(0, s0);
        stage(1, s0 + 64);

        qk_sm(s0, t < ntA);   // GLD latency hides under QK^T + softmax

        __syncthreads();      // vmcnt(0): V staged; Ps(t) drained

        pv(0, t < ntA);
        qk_sm(s0 + 64, t + 1 < ntA);

        asm volatile("s_waitcnt lgkmcnt(0)" ::: "memory");
        __builtin_amdgcn_sched_barrier(0);

        pv(1, t + 1 < ntA);
    }

    if (ntB & 1) {  // odd tail: single tile
        const int s0 = npair * 64;
        __syncthreads();
        stage(0, s0);
        qk_sm(s0, npair < ntA);
        __syncthreads();
        pv(0, npair < ntA);
    }

    // ---- normalize + store both strips ----
#pragma unroll
    for (int r = 0; r < 4; ++r) {
        int rowB = qB0 + wave * 16 + l4 * 4 + r;
        int rowA = qA0 + wave * 16 + l4 * 4 + r;
        float invB = 1.0f / sB[r];
        float invA = 1.0f / sA[r];
        size_t obB = ((size_t)b * T_ + rowB) * C_ + h * 64;
        size_t obA = ((size_t)b * T_ + rowA) * C_ + h * 64;
#pragma unroll
        for (int n = 0; n < 4; ++n) {
            out[obB + n * 16 + l15] = f2bf(OB[n][r] * invB);
            out[obA + n * 16 + l15] = f2bf(OA[n][r] * invA);
        }
    }
}

// ---------------------------------------------------------------------------
extern "C" void kernel_launch(void* const* d_in, const int* in_sizes, int n_in,
                              void* d_out, int out_size, void* d_ws, size_t ws_size,
                              hipStream_t stream) {
    const float* x     = (const float*)d_in[0];
    const float* wq    = (const float*)d_in[1];
    const float* wk    = (const float*)d_in[2];
    const float* wv    = (const float*)d_in[3];
    const float* wproj = (const float*)d_in[4];
    const float* bproj = (const float*)d_in[5];
    float* out = (float*)d_out;

    // workspace (shorts): wqkv_t | wproj_t | qk_b | vt_b | attn_b (xb alias)
    short* wqkv_t  = (short*)d_ws;                   // 3072*1024
    short* wproj_t = wqkv_t + 3072 * 1024;           // 1024*1024
    short* qk_b    = wproj_t + 1024 * 1024;          // 8192*2048  (Q|K)
    short* vt_b    = qk_b + (size_t)8192 * 2048;     // 64*64*2048 (V^T)
    short* attn_b  = vt_b + (size_t)64 * 64 * 2048;  // 8192*1024 (xb alias)
    short* xb      = attn_b;
    // total = 75,497,472 bytes (identical to all prior rounds)

    pack_x<<<4096, 256, 0, stream>>>(x, xb);
    pack_wqkv2<<<dim3(16, 48), 256, 0, stream>>>(wq, wk, wv, wqkv_t);
    pack_wproj2<<<dim3(16, 16), 256, 0, stream>>>(wproj, wproj_t);

    // QKV projection: Q(scaled)|K -> qk_b, V^T -> vt_b
    gemm_lds<2><<<dim3(24, 64), 256, 0, stream>>>(
        xb, wqkv_t, qk_b, vt_b, nullptr, 8192, 3072, 1024);

    // flash attention, pair-tile phases, GLD V-staging
    attn_v16<<<dim3(16, 64), 256, 0, stream>>>(qk_b, vt_b, attn_b);

    // output projection: [8192,1024] x [1024,1024] + bias -> fp32
    gemm_lds<1><<<dim3(8, 64), 256, 0, stream>>>(
        attn_b, wproj_t, out, nullptr, bproj, 8192, 1024, 1024);
}